// Round 2
// baseline (456.939 us; speedup 1.0000x reference)
//
#include <hip/hip_runtime.h>
#include <hip/hip_bf16.h>

#define NEG_SLOPE 0.2f
#define CAP 128   // max in-degree slots; in-degree ~ Poisson(33), P(deg>96) ~ 1e-19

__device__ __forceinline__ float lrelu(float x) { return x >= 0.f ? x : NEG_SLOPE * x; }

// ---------- dtype probe: int64 edge_index has zero high words ----------
__global__ void detect_i64(const int* __restrict__ ei, int* __restrict__ flag) {
    int t = threadIdx.x;                 // 64 threads
    int v = ei[2 * t + 1];               // odd int32 words of first 64 entries
    unsigned long long b = __ballot(v != 0);
    if (t == 0) flag[0] = (b == 0ULL) ? 1 : 0;   // 1 => int64 layout
}

// ---------- adjacency build (capped per-dst list, int atomics only) ----------
__global__ void build_adj(const int* __restrict__ ei, const int* __restrict__ flag,
                          int E, int N, int* __restrict__ cnt, int* __restrict__ adj) {
    int i = blockIdx.x * blockDim.x + threadIdx.x;
    int tot = E + N;
    if (i >= tot) return;
    int s, d;
    if (i < E) {
        if (flag[0]) {
            const long long* e64 = (const long long*)ei;
            s = (int)e64[i]; d = (int)e64[E + i];
        } else {
            s = ei[i]; d = ei[E + i];
        }
    } else { s = d = i - E; }            // PyG add_self_loops
    int pos = atomicAdd(&cnt[d], 1);
    if (pos < CAP) adj[(size_t)d * CAP + pos] = s;
}

// ---------- GEMM1: xp1[N,128] = x[N,128] @ W1[128,128], fp32 ----------
// 256 threads, 32 rows x 128 cols per block, 4x4 register tile, K split in halves
__global__ __launch_bounds__(256) void gemm1_kernel(const float* __restrict__ x,
        const float* __restrict__ W1, float* __restrict__ xp1, int N) {
    __shared__ __align__(16) float ws[64 * 128];   // 32KB: current K-half of W1
    __shared__ __align__(16) float xst[128 * 36];  // 18KB: x^T [k][r], pad 36
    int t = threadIdx.x;
    int row0 = blockIdx.x * 32;
    #pragma unroll
    for (int ii = 0; ii < 4; ++ii) {               // stage x transposed (float4 along k)
        int idx = t + 256 * ii;                    // 0..1023
        int r = idx >> 5, kq = idx & 31;
        int n = row0 + r;
        float4 v = make_float4(0.f, 0.f, 0.f, 0.f);
        if (n < N) v = *(const float4*)&x[(size_t)n * 128 + kq * 4];
        xst[(kq * 4 + 0) * 36 + r] = v.x;
        xst[(kq * 4 + 1) * 36 + r] = v.y;
        xst[(kq * 4 + 2) * 36 + r] = v.z;
        xst[(kq * 4 + 3) * 36 + r] = v.w;
    }
    int cg = t & 31, rg = t >> 5;
    float acc[4][4] = {};
    for (int half = 0; half < 2; ++half) {
        __syncthreads();                           // xst ready / ws safe to overwrite
        const float4* wsrc = (const float4*)(W1 + half * 64 * 128);
        float4* wdst = (float4*)ws;
        #pragma unroll
        for (int ii = 0; ii < 8; ++ii) wdst[t + 256 * ii] = wsrc[t + 256 * ii];
        __syncthreads();
        #pragma unroll 4
        for (int k = 0; k < 64; ++k) {
            float4 wv = *(const float4*)&ws[k * 128 + cg * 4];
            float4 xv = *(const float4*)&xst[(half * 64 + k) * 36 + rg * 4];
            float xr[4] = {xv.x, xv.y, xv.z, xv.w};
            float wr[4] = {wv.x, wv.y, wv.z, wv.w};
            #pragma unroll
            for (int r = 0; r < 4; ++r)
                #pragma unroll
                for (int c = 0; c < 4; ++c)
                    acc[r][c] = fmaf(xr[r], wr[c], acc[r][c]);
        }
    }
    #pragma unroll
    for (int r = 0; r < 4; ++r) {
        int n = row0 + rg * 4 + r;
        if (n < N)
            *(float4*)&xp1[(size_t)n * 128 + cg * 4] =
                make_float4(acc[r][0], acc[r][1], acc[r][2], acc[r][3]);
    }
}

// ---------- logits1: al_s/al_d [N,4] ----------
__global__ __launch_bounds__(128) void logits1_kernel(const float* __restrict__ xp1,
        const float* __restrict__ a_src, const float* __restrict__ a_dst,
        float* __restrict__ al_s, float* __restrict__ al_d, int N) {
    int n = blockIdx.x, t = threadIdx.x;   // t = h*32 + c
    float v = xp1[(size_t)n * 128 + t];
    float ps = v * a_src[t];
    float pd = v * a_dst[t];
    #pragma unroll
    for (int off = 16; off > 0; off >>= 1) {
        ps += __shfl_down(ps, off, 32);
        pd += __shfl_down(pd, off, 32);
    }
    if ((t & 31) == 0) {
        int h = t >> 5;
        al_s[n * 4 + h] = ps;
        al_d[n * 4 + h] = pd;
    }
}

// ---------- edge1: per-dst softmax + aggregate + bias + ELU -> h1 [N,128] ----------
__global__ __launch_bounds__(128) void edge1_kernel(const int* __restrict__ cnt,
        const int* __restrict__ adj, const float* __restrict__ al_s,
        const float* __restrict__ al_d, const float* __restrict__ xp1,
        const float* __restrict__ b1, float* __restrict__ h1, int N) {
    __shared__ int srcs[CAP];
    __shared__ __align__(16) float4 exv[CAP];
    __shared__ __align__(16) float4 red[128];
    int d = blockIdx.x, t = threadIdx.x;
    int deg = cnt[d]; if (deg > CAP) deg = CAP;
    float4 ex = make_float4(0.f, 0.f, 0.f, 0.f);
    if (t < deg) {
        int s = adj[(size_t)d * CAP + t];
        srcs[t] = s;
        float4 as = *(const float4*)&al_s[s * 4];
        float4 ad = *(const float4*)&al_d[d * 4];
        ex.x = expf(lrelu(as.x + ad.x));
        ex.y = expf(lrelu(as.y + ad.y));
        ex.z = expf(lrelu(as.z + ad.z));
        ex.w = expf(lrelu(as.w + ad.w));
    }
    exv[t] = ex; red[t] = ex;
    __syncthreads();
    #pragma unroll
    for (int off = 64; off > 0; off >>= 1) {
        if (t < off) {
            float4 a = red[t], b = red[t + off];
            a.x += b.x; a.y += b.y; a.z += b.z; a.w += b.w;
            red[t] = a;
        }
        __syncthreads();
    }
    float4 den = red[0];
    float4 al = ex;
    al.x /= (den.x + 1e-16f); al.y /= (den.y + 1e-16f);
    al.z /= (den.z + 1e-16f); al.w /= (den.w + 1e-16f);
    exv[t] = al;
    __syncthreads();
    int h = t >> 5;                       // thread t owns channel t
    float acc = 0.f;
    const float* ea = (const float*)exv;
    for (int i = 0; i < deg; ++i)
        acc += ea[i * 4 + h] * xp1[(size_t)srcs[i] * 128 + t];
    float v = acc + b1[t];
    h1[(size_t)d * 128 + t] = v > 0.f ? v : expm1f(v);   // ELU
}

// ---------- GEMM2: xp2[N,32] = h1[N,128] @ W2[128,32] ----------
__global__ __launch_bounds__(128) void gemm2_kernel(const float* __restrict__ h1,
        const float* __restrict__ W2, float* __restrict__ xp2, int N) {
    __shared__ __align__(16) float ws[128 * 32];   // 16KB
    __shared__ __align__(16) float xst[128 * 68];  // 35KB: h1^T, 64 rows, pad 68
    int t = threadIdx.x;
    int row0 = blockIdx.x * 64;
    const float4* wsrc = (const float4*)W2;
    float4* wdst = (float4*)ws;
    #pragma unroll
    for (int ii = 0; ii < 8; ++ii) wdst[t + 128 * ii] = wsrc[t + 128 * ii];
    #pragma unroll
    for (int ii = 0; ii < 16; ++ii) {
        int idx = t + 128 * ii;            // 0..2047
        int r = idx >> 5, kq = idx & 31;
        int n = row0 + r;
        float4 v = make_float4(0.f, 0.f, 0.f, 0.f);
        if (n < N) v = *(const float4*)&h1[(size_t)n * 128 + kq * 4];
        xst[(kq * 4 + 0) * 68 + r] = v.x;
        xst[(kq * 4 + 1) * 68 + r] = v.y;
        xst[(kq * 4 + 2) * 68 + r] = v.z;
        xst[(kq * 4 + 3) * 68 + r] = v.w;
    }
    __syncthreads();
    int cg = t & 7, rg = t >> 3;
    float acc[4][4] = {};
    #pragma unroll 4
    for (int k = 0; k < 128; ++k) {
        float4 wv = *(const float4*)&ws[k * 32 + cg * 4];
        float4 xv = *(const float4*)&xst[k * 68 + rg * 4];
        float xr[4] = {xv.x, xv.y, xv.z, xv.w};
        float wr[4] = {wv.x, wv.y, wv.z, wv.w};
        #pragma unroll
        for (int r = 0; r < 4; ++r)
            #pragma unroll
            for (int c = 0; c < 4; ++c)
                acc[r][c] = fmaf(xr[r], wr[c], acc[r][c]);
    }
    #pragma unroll
    for (int r = 0; r < 4; ++r) {
        int n = row0 + rg * 4 + r;
        if (n < N)
            *(float4*)&xp2[(size_t)n * 32 + cg * 4] =
                make_float4(acc[r][0], acc[r][1], acc[r][2], acc[r][3]);
    }
}

// ---------- logits2: al_s/al_d [N] ----------
__global__ __launch_bounds__(256) void logits2_kernel(const float* __restrict__ xp2,
        const float* __restrict__ a_src, const float* __restrict__ a_dst,
        float* __restrict__ al_s, float* __restrict__ al_d, int N) {
    int g = blockIdx.x * blockDim.x + threadIdx.x;
    int n = g >> 5, c = g & 31;
    if (n >= N) return;
    float v = xp2[(size_t)n * 32 + c];
    float ps = v * a_src[c];
    float pd = v * a_dst[c];
    #pragma unroll
    for (int off = 16; off > 0; off >>= 1) {
        ps += __shfl_down(ps, off, 32);
        pd += __shfl_down(pd, off, 32);
    }
    if (c == 0) { al_s[n] = ps; al_d[n] = pd; }
}

// ---------- edge2: per-dst softmax + aggregate + bias -> out [N,32] fp32 ----------
__global__ __launch_bounds__(128) void edge2_kernel(const int* __restrict__ cnt,
        const int* __restrict__ adj, const float* __restrict__ al_s,
        const float* __restrict__ al_d, const float* __restrict__ xp2,
        const float* __restrict__ b2v, float* __restrict__ out, int N) {
    __shared__ int srcs[CAP];
    __shared__ float exv[CAP];
    __shared__ float red[128];
    int d = blockIdx.x, t = threadIdx.x;
    int deg = cnt[d]; if (deg > CAP) deg = CAP;
    float ex = 0.f;
    if (t < deg) {
        int s = adj[(size_t)d * CAP + t];
        srcs[t] = s;
        ex = expf(lrelu(al_s[s] + al_d[d]));
    }
    exv[t] = ex; red[t] = ex;
    __syncthreads();
    #pragma unroll
    for (int off = 64; off > 0; off >>= 1) {
        if (t < off) red[t] += red[t + off];
        __syncthreads();
    }
    float den = red[0];
    exv[t] = ex / (den + 1e-16f);
    __syncthreads();
    int c = t & 31, q = t >> 5;
    float acc = 0.f;
    for (int i = q; i < deg; i += 4)
        acc += exv[i] * xp2[(size_t)srcs[i] * 32 + c];
    red[t] = acc;
    __syncthreads();
    if (t < 32) {
        float s = red[t] + red[t + 32] + red[t + 64] + red[t + 96];
        out[(size_t)d * 32 + t] = s + b2v[t];
    }
}

extern "C" void kernel_launch(void* const* d_in, const int* in_sizes, int n_in,
                              void* d_out, int out_size, void* d_ws, size_t ws_size,
                              hipStream_t stream) {
    const float* x    = (const float*)d_in[0];
    const int*   ei   = (const int*)d_in[1];
    const float* W1   = (const float*)d_in[2];
    const float* a_s1 = (const float*)d_in[3];
    const float* a_d1 = (const float*)d_in[4];
    const float* b1   = (const float*)d_in[5];
    const float* W2   = (const float*)d_in[6];
    const float* a_s2 = (const float*)d_in[7];
    const float* a_d2 = (const float*)d_in[8];
    const float* b2   = (const float*)d_in[9];
    int N = in_sizes[0] / 128;
    int E = in_sizes[1] / 2;
    float* out = (float*)d_out;

    char* wsb = (char*)d_ws;
    size_t off = 0;
    auto alloc = [&](size_t bytes) -> void* {
        void* p = wsb + off;
        off = (off + bytes + 255) & ~(size_t)255;
        return p;
    };
    int*   flag  = (int*)  alloc(4);
    int*   cnt   = (int*)  alloc((size_t)N * 4);
    int*   adj   = (int*)  alloc((size_t)N * CAP * 4);
    float* xp1   = (float*)alloc((size_t)N * 128 * 4);
    float* al_s1 = (float*)alloc((size_t)N * 4 * 4);
    float* al_d1 = (float*)alloc((size_t)N * 4 * 4);
    float* h1    = (float*)alloc((size_t)N * 128 * 4);
    // aliases (xp1 / al_*1 dead after edge1)
    float* xp2    = xp1;
    float* al_s2v = al_s1;
    float* al_d2v = al_d1;

    hipMemsetAsync(cnt, 0, (size_t)N * 4, stream);
    detect_i64<<<1, 64, 0, stream>>>(ei, flag);
    int tot = E + N;
    build_adj<<<(tot + 255) / 256, 256, 0, stream>>>(ei, flag, E, N, cnt, adj);
    gemm1_kernel<<<(N + 31) / 32, 256, 0, stream>>>(x, W1, xp1, N);
    logits1_kernel<<<N, 128, 0, stream>>>(xp1, a_s1, a_d1, al_s1, al_d1, N);
    edge1_kernel<<<N, 128, 0, stream>>>(cnt, adj, al_s1, al_d1, xp1, b1, h1, N);
    gemm2_kernel<<<(N + 63) / 64, 128, 0, stream>>>(h1, W2, xp2, N);
    logits2_kernel<<<((size_t)N * 32 + 255) / 256, 256, 0, stream>>>(xp2, a_s2, a_d2, al_s2v, al_d2v, N);
    edge2_kernel<<<N, 128, 0, stream>>>(cnt, adj, al_s2v, al_d2v, xp2, b2, out, N);
}

// Round 3
// 395.282 us; speedup vs baseline: 1.1560x; 1.1560x over previous
//
#include <hip/hip_runtime.h>

#define NEG_SLOPE 0.2f
#define CAP 128     // max in-degree slots; in-degree ~ Poisson(33), P(deg>96) ~ 1e-19
#define NB  64      // coarse dst bins
#define GAB 192     // blocks for count/bin passes (partials fit in 48KB LDS for scan)
#define SUBS 32     // blocks per bin in fill phase

__device__ __forceinline__ float lrelu(float x) { return x >= 0.f ? x : NEG_SLOPE * x; }

// ---------- dtype probe: int64 edge_index has zero high words ----------
__global__ void detect_i64(const int* __restrict__ ei, int E, int* __restrict__ flag) {
    int t = threadIdx.x;                 // 64 threads
    int idx = 2 * t + 1; if (idx >= 2 * E) idx = 2 * E - 1;
    int v = ei[idx];
    unsigned long long b = __ballot(v != 0);
    if (t == 0) flag[0] = (b == 0ULL) ? 1 : 0;   // 1 => int64 layout
}

__device__ __forceinline__ void load_edge(const int* __restrict__ ei, int E, int i,
                                          bool is64, int& s, int& d) {
    if (i < E) {
        if (is64) { const long long* e = (const long long*)ei; s = (int)e[i]; d = (int)e[E + i]; }
        else      { s = ei[i]; d = ei[E + i]; }
    } else { s = d = i - E; }            // PyG add_self_loops
}

// ---------- phase 1: per-block per-bin counts ----------
__global__ __launch_bounds__(256) void k_count(const int* __restrict__ ei,
        const int* __restrict__ flag, int E, int N, int shift, int* __restrict__ partials) {
    __shared__ int cnts[NB];
    int t = threadIdx.x, b = blockIdx.x;
    if (t < NB) cnts[t] = 0;
    __syncthreads();
    bool is64 = flag[0] != 0;
    int tot = E + N;
    for (int i = b * 256 + t; i < tot; i += GAB * 256) {
        int s, d; load_edge(ei, E, i, is64, s, d);
        atomicAdd(&cnts[d >> shift], 1);
    }
    __syncthreads();
    if (t < NB) partials[b * NB + t] = cnts[t];
}

// ---------- phase 2: scan -> per-(block,bin) write offsets + bin bases ----------
__global__ __launch_bounds__(256) void k_scan(int* __restrict__ partials,
                                              int* __restrict__ bin_base) {
    __shared__ int lp[GAB * NB];    // 48KB
    __shared__ int tot[NB], base[NB];
    int t = threadIdx.x;
    for (int i = t; i < GAB * NB; i += 256) lp[i] = partials[i];
    __syncthreads();
    if (t < NB) {                    // exclusive scan across blocks, per bin
        int run = 0;
        for (int b = 0; b < GAB; ++b) { int v = lp[b * NB + t]; lp[b * NB + t] = run; run += v; }
        tot[t] = run;
    }
    __syncthreads();
    if (t == 0) {                    // exclusive scan across bins
        int run = 0;
        for (int i = 0; i < NB; ++i) { base[i] = run; run += tot[i]; }
    }
    __syncthreads();
    if (t < NB) bin_base[t] = base[t];
    if (t == 0) bin_base[NB] = base[NB - 1] + tot[NB - 1];
    for (int i = t; i < GAB * NB; i += 256) partials[i] = lp[i] + base[i & (NB - 1)];
}

// ---------- phase 3: scatter edges into bins (coalesced-ish, LDS cursors) ----------
__global__ __launch_bounds__(256) void k_bin(const int* __restrict__ ei,
        const int* __restrict__ flag, int E, int N, int shift,
        const int* __restrict__ offsets, int2* __restrict__ binned) {
    __shared__ int cur[NB];
    int t = threadIdx.x, b = blockIdx.x;
    if (t < NB) cur[t] = offsets[b * NB + t];
    __syncthreads();
    bool is64 = flag[0] != 0;
    int tot = E + N;
    for (int i = b * 256 + t; i < tot; i += GAB * 256) {
        int s, d; load_edge(ei, E, i, is64, s, d);
        int pos = atomicAdd(&cur[d >> shift], 1);
        binned[pos] = make_int2(s, d);
    }
}

// ---------- phase 4: fill adj; bin -> fixed blockIdx%8 residue => XCD-local L2 ----------
__global__ __launch_bounds__(256) void k_fill(const int2* __restrict__ binned,
        const int* __restrict__ bin_base, int* __restrict__ cnt, int* __restrict__ adj) {
    int t = threadIdx.x;
    int bin = blockIdx.x & (NB - 1);
    int sub = blockIdx.x >> 6;
    int lo = bin_base[bin], hi = bin_base[bin + 1];
    for (int i = lo + sub * 256 + t; i < hi; i += SUBS * 256) {
        int2 e = binned[i];
        int pos = atomicAdd(&cnt[e.y], 1);
        if (pos < CAP) adj[(size_t)e.y * CAP + pos] = e.x;
    }
}

// ---------- GEMM1 + fused logits1 ----------
// 256 threads, 32 rows x 128 cols, 4x4 register tile, K split in halves
__global__ __launch_bounds__(256) void gemm1_kernel(const float* __restrict__ x,
        const float* __restrict__ W1, const float* __restrict__ a_src,
        const float* __restrict__ a_dst, float* __restrict__ xp1,
        float* __restrict__ al_s, float* __restrict__ al_d, int N) {
    __shared__ __align__(16) float ws[64 * 128];
    __shared__ __align__(16) float xst[128 * 36];
    int t = threadIdx.x;
    int row0 = blockIdx.x * 32;
    #pragma unroll
    for (int ii = 0; ii < 4; ++ii) {
        int idx = t + 256 * ii;
        int r = idx >> 5, kq = idx & 31;
        int n = row0 + r;
        float4 v = make_float4(0.f, 0.f, 0.f, 0.f);
        if (n < N) v = *(const float4*)&x[(size_t)n * 128 + kq * 4];
        xst[(kq * 4 + 0) * 36 + r] = v.x;
        xst[(kq * 4 + 1) * 36 + r] = v.y;
        xst[(kq * 4 + 2) * 36 + r] = v.z;
        xst[(kq * 4 + 3) * 36 + r] = v.w;
    }
    int cg = t & 31, rg = t >> 5;
    float acc[4][4] = {};
    for (int half = 0; half < 2; ++half) {
        __syncthreads();
        const float4* wsrc = (const float4*)(W1 + half * 64 * 128);
        float4* wdst = (float4*)ws;
        #pragma unroll
        for (int ii = 0; ii < 8; ++ii) wdst[t + 256 * ii] = wsrc[t + 256 * ii];
        __syncthreads();
        #pragma unroll 4
        for (int k = 0; k < 64; ++k) {
            float4 wv = *(const float4*)&ws[k * 128 + cg * 4];
            float4 xv = *(const float4*)&xst[(half * 64 + k) * 36 + rg * 4];
            float xr[4] = {xv.x, xv.y, xv.z, xv.w};
            float wr[4] = {wv.x, wv.y, wv.z, wv.w};
            #pragma unroll
            for (int r = 0; r < 4; ++r)
                #pragma unroll
                for (int c = 0; c < 4; ++c)
                    acc[r][c] = fmaf(xr[r], wr[c], acc[r][c]);
        }
    }
    #pragma unroll
    for (int r = 0; r < 4; ++r) {
        int n = row0 + rg * 4 + r;
        if (n < N)
            *(float4*)&xp1[(size_t)n * 128 + cg * 4] =
                make_float4(acc[r][0], acc[r][1], acc[r][2], acc[r][3]);
    }
    // fused logits: head = cg>>3; columns cg*4..cg*4+3
    float ps[4], pd[4];
    #pragma unroll
    for (int r = 0; r < 4; ++r) {
        float s = 0.f, dd = 0.f;
        #pragma unroll
        for (int c = 0; c < 4; ++c) {
            s  = fmaf(acc[r][c], a_src[cg * 4 + c], s);
            dd = fmaf(acc[r][c], a_dst[cg * 4 + c], dd);
        }
        ps[r] = s; pd[r] = dd;
    }
    #pragma unroll
    for (int m = 1; m < 8; m <<= 1) {
        #pragma unroll
        for (int r = 0; r < 4; ++r) { ps[r] += __shfl_xor(ps[r], m); pd[r] += __shfl_xor(pd[r], m); }
    }
    if ((cg & 7) == 0) {
        int head = cg >> 3;
        #pragma unroll
        for (int r = 0; r < 4; ++r) {
            int n = row0 + rg * 4 + r;
            if (n < N) { al_s[n * 4 + head] = ps[r]; al_d[n * 4 + head] = pd[r]; }
        }
    }
}

// ---------- edge1: per-dst softmax + aggregate + bias + ELU -> h1 [N,128] ----------
__global__ __launch_bounds__(128) void edge1_kernel(const int* __restrict__ cnt,
        const int* __restrict__ adj, const float* __restrict__ al_s,
        const float* __restrict__ al_d, const float* __restrict__ xp1,
        const float* __restrict__ b1, float* __restrict__ h1, int N) {
    __shared__ int srcs[CAP];
    __shared__ __align__(16) float4 exv[CAP];
    __shared__ __align__(16) float4 red[128];
    int d = blockIdx.x, t = threadIdx.x;
    int deg = cnt[d]; if (deg > CAP) deg = CAP;
    float4 ex = make_float4(0.f, 0.f, 0.f, 0.f);
    if (t < deg) {
        int s = adj[(size_t)d * CAP + t];
        srcs[t] = s;
        float4 as = *(const float4*)&al_s[s * 4];
        float4 ad = *(const float4*)&al_d[d * 4];
        ex.x = expf(lrelu(as.x + ad.x));
        ex.y = expf(lrelu(as.y + ad.y));
        ex.z = expf(lrelu(as.z + ad.z));
        ex.w = expf(lrelu(as.w + ad.w));
    }
    exv[t] = ex; red[t] = ex;
    __syncthreads();
    #pragma unroll
    for (int off = 64; off > 0; off >>= 1) {
        if (t < off) {
            float4 a = red[t], b = red[t + off];
            a.x += b.x; a.y += b.y; a.z += b.z; a.w += b.w;
            red[t] = a;
        }
        __syncthreads();
    }
    float4 den = red[0];
    float4 al = ex;
    al.x /= (den.x + 1e-16f); al.y /= (den.y + 1e-16f);
    al.z /= (den.z + 1e-16f); al.w /= (den.w + 1e-16f);
    exv[t] = al;
    __syncthreads();
    int h = t >> 5;                       // thread t owns channel t
    const float* ea = (const float*)exv;
    float a0 = 0.f, a1 = 0.f, a2 = 0.f, a3 = 0.f;
    int i = 0;
    for (; i + 4 <= deg; i += 4) {
        int s0 = srcs[i], s1 = srcs[i + 1], s2 = srcs[i + 2], s3 = srcs[i + 3];
        float w0 = ea[(i + 0) * 4 + h], w1 = ea[(i + 1) * 4 + h];
        float w2 = ea[(i + 2) * 4 + h], w3 = ea[(i + 3) * 4 + h];
        a0 = fmaf(w0, xp1[(size_t)s0 * 128 + t], a0);
        a1 = fmaf(w1, xp1[(size_t)s1 * 128 + t], a1);
        a2 = fmaf(w2, xp1[(size_t)s2 * 128 + t], a2);
        a3 = fmaf(w3, xp1[(size_t)s3 * 128 + t], a3);
    }
    for (; i < deg; ++i)
        a0 = fmaf(ea[i * 4 + h], xp1[(size_t)srcs[i] * 128 + t], a0);
    float v = a0 + a1 + a2 + a3 + b1[t];
    h1[(size_t)d * 128 + t] = v > 0.f ? v : expm1f(v);   // ELU
}

// ---------- GEMM2 + fused logits2 ----------
__global__ __launch_bounds__(128) void gemm2_kernel(const float* __restrict__ h1,
        const float* __restrict__ W2, const float* __restrict__ a_src,
        const float* __restrict__ a_dst, float* __restrict__ xp2,
        float* __restrict__ al_s, float* __restrict__ al_d, int N) {
    __shared__ __align__(16) float ws[128 * 32];
    __shared__ __align__(16) float xst[128 * 68];
    int t = threadIdx.x;
    int row0 = blockIdx.x * 64;
    const float4* wsrc = (const float4*)W2;
    float4* wdst = (float4*)ws;
    #pragma unroll
    for (int ii = 0; ii < 8; ++ii) wdst[t + 128 * ii] = wsrc[t + 128 * ii];
    #pragma unroll
    for (int ii = 0; ii < 16; ++ii) {
        int idx = t + 128 * ii;
        int r = idx >> 5, kq = idx & 31;
        int n = row0 + r;
        float4 v = make_float4(0.f, 0.f, 0.f, 0.f);
        if (n < N) v = *(const float4*)&h1[(size_t)n * 128 + kq * 4];
        xst[(kq * 4 + 0) * 68 + r] = v.x;
        xst[(kq * 4 + 1) * 68 + r] = v.y;
        xst[(kq * 4 + 2) * 68 + r] = v.z;
        xst[(kq * 4 + 3) * 68 + r] = v.w;
    }
    __syncthreads();
    int cg = t & 7, rg = t >> 3;
    float acc[4][4] = {};
    #pragma unroll 4
    for (int k = 0; k < 128; ++k) {
        float4 wv = *(const float4*)&ws[k * 32 + cg * 4];
        float4 xv = *(const float4*)&xst[k * 68 + rg * 4];
        float xr[4] = {xv.x, xv.y, xv.z, xv.w};
        float wr[4] = {wv.x, wv.y, wv.z, wv.w};
        #pragma unroll
        for (int r = 0; r < 4; ++r)
            #pragma unroll
            for (int c = 0; c < 4; ++c)
                acc[r][c] = fmaf(xr[r], wr[c], acc[r][c]);
    }
    #pragma unroll
    for (int r = 0; r < 4; ++r) {
        int n = row0 + rg * 4 + r;
        if (n < N)
            *(float4*)&xp2[(size_t)n * 32 + cg * 4] =
                make_float4(acc[r][0], acc[r][1], acc[r][2], acc[r][3]);
    }
    // fused logits2 (single head over 32 cols)
    float ps[4], pd[4];
    #pragma unroll
    for (int r = 0; r < 4; ++r) {
        float s = 0.f, dd = 0.f;
        #pragma unroll
        for (int c = 0; c < 4; ++c) {
            s  = fmaf(acc[r][c], a_src[cg * 4 + c], s);
            dd = fmaf(acc[r][c], a_dst[cg * 4 + c], dd);
        }
        ps[r] = s; pd[r] = dd;
    }
    #pragma unroll
    for (int m = 1; m < 8; m <<= 1) {
        #pragma unroll
        for (int r = 0; r < 4; ++r) { ps[r] += __shfl_xor(ps[r], m); pd[r] += __shfl_xor(pd[r], m); }
    }
    if (cg == 0) {
        #pragma unroll
        for (int r = 0; r < 4; ++r) {
            int n = row0 + rg * 4 + r;
            if (n < N) { al_s[n] = ps[r]; al_d[n] = pd[r]; }
        }
    }
}

// ---------- edge2: per-dst softmax + aggregate + bias -> out [N,32] ----------
__global__ __launch_bounds__(128) void edge2_kernel(const int* __restrict__ cnt,
        const int* __restrict__ adj, const float* __restrict__ al_s,
        const float* __restrict__ al_d, const float* __restrict__ xp2,
        const float* __restrict__ b2v, float* __restrict__ out, int N) {
    __shared__ int srcs[CAP];
    __shared__ float exv[CAP];
    __shared__ float red[128];
    int d = blockIdx.x, t = threadIdx.x;
    int deg = cnt[d]; if (deg > CAP) deg = CAP;
    float ex = 0.f;
    if (t < deg) {
        int s = adj[(size_t)d * CAP + t];
        srcs[t] = s;
        ex = expf(lrelu(al_s[s] + al_d[d]));
    }
    exv[t] = ex; red[t] = ex;
    __syncthreads();
    #pragma unroll
    for (int off = 64; off > 0; off >>= 1) {
        if (t < off) red[t] += red[t + off];
        __syncthreads();
    }
    float den = red[0];
    exv[t] = ex / (den + 1e-16f);
    __syncthreads();
    int c = t & 31, q = t >> 5;
    float a0 = 0.f, a1 = 0.f;
    int i = q;
    for (; i + 4 < deg; i += 8) {
        a0 = fmaf(exv[i],     xp2[(size_t)srcs[i]     * 32 + c], a0);
        a1 = fmaf(exv[i + 4], xp2[(size_t)srcs[i + 4] * 32 + c], a1);
    }
    if (i < deg)
        a0 = fmaf(exv[i], xp2[(size_t)srcs[i] * 32 + c], a0);
    red[t] = a0 + a1;
    __syncthreads();
    if (t < 32) {
        float s = red[t] + red[t + 32] + red[t + 64] + red[t + 96];
        out[(size_t)d * 32 + t] = s + b2v[t];
    }
}

extern "C" void kernel_launch(void* const* d_in, const int* in_sizes, int n_in,
                              void* d_out, int out_size, void* d_ws, size_t ws_size,
                              hipStream_t stream) {
    const float* x    = (const float*)d_in[0];
    const int*   ei   = (const int*)d_in[1];
    const float* W1   = (const float*)d_in[2];
    const float* a_s1 = (const float*)d_in[3];
    const float* a_d1 = (const float*)d_in[4];
    const float* b1   = (const float*)d_in[5];
    const float* W2   = (const float*)d_in[6];
    const float* a_s2 = (const float*)d_in[7];
    const float* a_d2 = (const float*)d_in[8];
    const float* b2   = (const float*)d_in[9];
    int N = in_sizes[0] / 128;
    int E = in_sizes[1] / 2;
    float* out = (float*)d_out;

    int shift = 0;
    while (((N - 1) >> shift) >= NB) shift++;

    char* wsb = (char*)d_ws;
    size_t off = 0;
    auto alloc = [&](size_t bytes) -> void* {
        void* p = wsb + off;
        off = (off + bytes + 255) & ~(size_t)255;
        return p;
    };
    int*   flag     = (int*)  alloc(4);
    int*   cnt      = (int*)  alloc((size_t)N * 4);
    int*   adj      = (int*)  alloc((size_t)N * CAP * 4);
    int*   partials = (int*)  alloc((size_t)GAB * NB * 4);
    int*   bin_base = (int*)  alloc((size_t)(NB + 1) * 4);
    float* xp1      = (float*)alloc((size_t)N * 128 * 4);
    float* al_s1    = (float*)alloc((size_t)N * 4 * 4);
    float* al_d1    = (float*)alloc((size_t)N * 4 * 4);
    float* h1       = (float*)alloc((size_t)N * 128 * 4);
    // aliases: binned (dead after k_fill) shares h1 (written later by edge1);
    // layer-2 buffers reuse dead layer-1 buffers
    int2*  binned   = (int2*)h1;        // needs (E+N)*8 <= N*512  (13.6MB <= 25.6MB)
    float* xp2      = xp1;
    float* al_s2v   = al_s1;
    float* al_d2v   = al_d1;

    hipMemsetAsync(cnt, 0, (size_t)N * 4, stream);
    detect_i64<<<1, 64, 0, stream>>>(ei, E, flag);
    k_count<<<GAB, 256, 0, stream>>>(ei, flag, E, N, shift, partials);
    k_scan<<<1, 256, 0, stream>>>(partials, bin_base);
    k_bin<<<GAB, 256, 0, stream>>>(ei, flag, E, N, shift, partials, binned);
    k_fill<<<NB * SUBS, 256, 0, stream>>>(binned, bin_base, cnt, adj);
    gemm1_kernel<<<(N + 31) / 32, 256, 0, stream>>>(x, W1, a_s1, a_d1, xp1, al_s1, al_d1, N);
    edge1_kernel<<<N, 128, 0, stream>>>(cnt, adj, al_s1, al_d1, xp1, b1, h1, N);
    gemm2_kernel<<<(N + 63) / 64, 128, 0, stream>>>(h1, W2, a_s2, a_d2, xp2, al_s2v, al_d2v, N);
    edge2_kernel<<<N, 128, 0, stream>>>(cnt, adj, al_s2v, al_d2v, xp2, b2, out, N);
}

// Round 4
// 324.168 us; speedup vs baseline: 1.4096x; 1.2194x over previous
//
#include <hip/hip_runtime.h>
#include <hip/hip_fp16.h>

#define NEG_SLOPE 0.2f
#define CAP 128     // max in-degree slots; in-degree ~ Poisson(33), P(deg>96) ~ 1e-19
#define NB  64      // coarse dst bins
#define GAB 192     // blocks for count/bin passes
#define SUBS 32     // blocks per bin in fill phase

typedef __half half_t;

__device__ __forceinline__ float lrelu(float x) { return x >= 0.f ? x : NEG_SLOPE * x; }

__device__ __forceinline__ float2 h2f2(unsigned int u) {
    union { unsigned int u; __half2 h; } v; v.u = u;
    return __half22float2(v.h);
}
__device__ __forceinline__ unsigned int f2h2(float a, float b) {
    union { unsigned int u; __half2 h; } v; v.h = __floats2half2_rn(a, b);
    return v.u;
}

// int64 edge_index detection: odd int32 words of first 64 entries are all zero
__device__ __forceinline__ bool edge_is64(const int* __restrict__ ei, int E) {
    int t = threadIdx.x & 63;
    int idx = 2 * t + 1; if (idx >= 2 * E) idx = 2 * E - 1;
    unsigned long long b = __ballot(ei[idx] != 0);
    return b == 0ULL;
}

__device__ __forceinline__ void load_edge(const int* __restrict__ ei, int E, int i,
                                          bool is64, int& s, int& d) {
    if (i < E) {
        if (is64) { const long long* e = (const long long*)ei; s = (int)e[i]; d = (int)e[E + i]; }
        else      { s = ei[i]; d = ei[E + i]; }
    } else { s = d = i - E; }            // PyG add_self_loops
}

// ---------- phase 1: per-block per-bin counts (+ zero cnt for k_fill) ----------
__global__ __launch_bounds__(256) void k_count(const int* __restrict__ ei,
        int E, int N, int shift, int* __restrict__ partials, int* __restrict__ cnt) {
    __shared__ int cnts[NB];
    int t = threadIdx.x, b = blockIdx.x;
    if (t < NB) cnts[t] = 0;
    bool is64 = edge_is64(ei, E);
    for (int i = b * 256 + t; i < N; i += GAB * 256) cnt[i] = 0;
    __syncthreads();
    int tot = E + N;
    for (int i = b * 256 + t; i < tot; i += GAB * 256) {
        int s, d; load_edge(ei, E, i, is64, s, d);
        atomicAdd(&cnts[d >> shift], 1);
    }
    __syncthreads();
    if (t < NB) partials[b * NB + t] = cnts[t];
}

// ---------- phase 2: scan -> per-(block,bin) write offsets + bin bases ----------
__global__ __launch_bounds__(256) void k_scan(int* __restrict__ partials,
                                              int* __restrict__ bin_base) {
    __shared__ int lp[GAB * NB];    // 48KB
    __shared__ int tot[NB], base[NB];
    int t = threadIdx.x;
    for (int i = t; i < GAB * NB; i += 256) lp[i] = partials[i];
    __syncthreads();
    if (t < NB) {
        int run = 0;
        for (int b = 0; b < GAB; ++b) { int v = lp[b * NB + t]; lp[b * NB + t] = run; run += v; }
        tot[t] = run;
    }
    __syncthreads();
    if (t == 0) {
        int run = 0;
        for (int i = 0; i < NB; ++i) { base[i] = run; run += tot[i]; }
    }
    __syncthreads();
    if (t < NB) bin_base[t] = base[t];
    if (t == 0) bin_base[NB] = base[NB - 1] + tot[NB - 1];
    for (int i = t; i < GAB * NB; i += 256) partials[i] = lp[i] + base[i & (NB - 1)];
}

// ---------- phase 3: scatter edges into dst bins (LDS cursors) ----------
__global__ __launch_bounds__(256) void k_bin(const int* __restrict__ ei,
        int E, int N, int shift, const int* __restrict__ offsets, int2* __restrict__ binned) {
    __shared__ int cur[NB];
    int t = threadIdx.x, b = blockIdx.x;
    if (t < NB) cur[t] = offsets[b * NB + t];
    bool is64 = edge_is64(ei, E);
    __syncthreads();
    int tot = E + N;
    for (int i = b * 256 + t; i < tot; i += GAB * 256) {
        int s, d; load_edge(ei, E, i, is64, s, d);
        int pos = atomicAdd(&cur[d >> shift], 1);
        binned[pos] = make_int2(s, d);
    }
}

// ---------- phase 4: fill adj; bin -> fixed blockIdx%NB residue => XCD-local L2 ----------
__global__ __launch_bounds__(256) void k_fill(const int2* __restrict__ binned,
        const int* __restrict__ bin_base, int* __restrict__ cnt, int* __restrict__ adj) {
    int t = threadIdx.x;
    int bin = blockIdx.x & (NB - 1);
    int sub = blockIdx.x >> 6;
    int lo = bin_base[bin], hi = bin_base[bin + 1];
    for (int i = lo + sub * 256 + t; i < hi; i += SUBS * 256) {
        int2 e = binned[i];
        int pos = atomicAdd(&cnt[e.y], 1);
        if (pos < CAP) adj[(size_t)e.y * CAP + pos] = e.x;
    }
}

// ---------- GEMM1 + fused logits1, fp16 output ----------
__global__ __launch_bounds__(256) void gemm1_kernel(const float* __restrict__ x,
        const float* __restrict__ W1, const float* __restrict__ a_src,
        const float* __restrict__ a_dst, half_t* __restrict__ xp1h,
        float* __restrict__ al_s, float* __restrict__ al_d, int N) {
    __shared__ __align__(16) float ws[64 * 128];
    __shared__ __align__(16) float xst[128 * 36];
    int t = threadIdx.x;
    int row0 = blockIdx.x * 32;
    #pragma unroll
    for (int ii = 0; ii < 4; ++ii) {
        int idx = t + 256 * ii;
        int r = idx >> 5, kq = idx & 31;
        int n = row0 + r;
        float4 v = make_float4(0.f, 0.f, 0.f, 0.f);
        if (n < N) v = *(const float4*)&x[(size_t)n * 128 + kq * 4];
        xst[(kq * 4 + 0) * 36 + r] = v.x;
        xst[(kq * 4 + 1) * 36 + r] = v.y;
        xst[(kq * 4 + 2) * 36 + r] = v.z;
        xst[(kq * 4 + 3) * 36 + r] = v.w;
    }
    int cg = t & 31, rg = t >> 5;
    float acc[4][4] = {};
    for (int half = 0; half < 2; ++half) {
        __syncthreads();
        const float4* wsrc = (const float4*)(W1 + half * 64 * 128);
        float4* wdst = (float4*)ws;
        #pragma unroll
        for (int ii = 0; ii < 8; ++ii) wdst[t + 256 * ii] = wsrc[t + 256 * ii];
        __syncthreads();
        #pragma unroll 4
        for (int k = 0; k < 64; ++k) {
            float4 wv = *(const float4*)&ws[k * 128 + cg * 4];
            float4 xv = *(const float4*)&xst[(half * 64 + k) * 36 + rg * 4];
            float xr[4] = {xv.x, xv.y, xv.z, xv.w};
            float wr[4] = {wv.x, wv.y, wv.z, wv.w};
            #pragma unroll
            for (int r = 0; r < 4; ++r)
                #pragma unroll
                for (int c = 0; c < 4; ++c)
                    acc[r][c] = fmaf(xr[r], wr[c], acc[r][c]);
        }
    }
    #pragma unroll
    for (int r = 0; r < 4; ++r) {
        int n = row0 + rg * 4 + r;
        if (n < N) {
            uint2 u = make_uint2(f2h2(acc[r][0], acc[r][1]), f2h2(acc[r][2], acc[r][3]));
            *(uint2*)&xp1h[(size_t)n * 128 + cg * 4] = u;
        }
    }
    // fused logits: head = cg>>3
    float ps[4], pd[4];
    #pragma unroll
    for (int r = 0; r < 4; ++r) {
        float s = 0.f, dd = 0.f;
        #pragma unroll
        for (int c = 0; c < 4; ++c) {
            s  = fmaf(acc[r][c], a_src[cg * 4 + c], s);
            dd = fmaf(acc[r][c], a_dst[cg * 4 + c], dd);
        }
        ps[r] = s; pd[r] = dd;
    }
    #pragma unroll
    for (int m = 1; m < 8; m <<= 1) {
        #pragma unroll
        for (int r = 0; r < 4; ++r) { ps[r] += __shfl_xor(ps[r], m); pd[r] += __shfl_xor(pd[r], m); }
    }
    if ((cg & 7) == 0) {
        int head = cg >> 3;
        #pragma unroll
        for (int r = 0; r < 4; ++r) {
            int n = row0 + rg * 4 + r;
            if (n < N) { al_s[n * 4 + head] = ps[r]; al_d[n * 4 + head] = pd[r]; }
        }
    }
}

// ---------- edge1: softmax + fp16 gather (16 lanes/edge, 8 edges in flight) ----------
__global__ __launch_bounds__(128) void edge1_kernel(const int* __restrict__ cnt,
        const int* __restrict__ adj, const float* __restrict__ al_s,
        const float* __restrict__ al_d, const half_t* __restrict__ xp1h,
        const float* __restrict__ b1, float* __restrict__ h1, int N) {
    __shared__ int srcs[CAP];
    __shared__ float ew[CAP * 4];
    __shared__ __align__(16) float red[8 * 128];
    __shared__ float4 wden[2];
    int d = blockIdx.x, t = threadIdx.x;
    int deg = cnt[d]; if (deg > CAP) deg = CAP;
    float4 ex = make_float4(0.f, 0.f, 0.f, 0.f);
    if (t < deg) {
        int s = adj[(size_t)d * CAP + t];
        srcs[t] = s;
        float4 as = *(const float4*)&al_s[s * 4];
        float4 ad = *(const float4*)&al_d[d * 4];
        ex.x = expf(lrelu(as.x + ad.x));
        ex.y = expf(lrelu(as.y + ad.y));
        ex.z = expf(lrelu(as.z + ad.z));
        ex.w = expf(lrelu(as.w + ad.w));
    }
    float4 r = ex;
    #pragma unroll
    for (int m = 1; m < 64; m <<= 1) {
        r.x += __shfl_xor(r.x, m); r.y += __shfl_xor(r.y, m);
        r.z += __shfl_xor(r.z, m); r.w += __shfl_xor(r.w, m);
    }
    if ((t & 63) == 0) wden[t >> 6] = r;
    __syncthreads();
    float4 den = wden[0], dn1 = wden[1];
    den.x += dn1.x; den.y += dn1.y; den.z += dn1.z; den.w += dn1.w;
    if (t < deg) {
        float4 al;
        al.x = ex.x / (den.x + 1e-16f); al.y = ex.y / (den.y + 1e-16f);
        al.z = ex.z / (den.z + 1e-16f); al.w = ex.w / (den.w + 1e-16f);
        *(float4*)&ew[t * 4] = al;
    }
    __syncthreads();
    int q = t & 15, p = t >> 4, h = q >> 2;   // lane-group q owns channels 8q..8q+7
    float a[8] = {};
    const uint4* xr = (const uint4*)xp1h;     // row = 16 uint4
    for (int i = p; i < deg; i += 8) {
        int s = srcs[i];
        float w = ew[i * 4 + h];
        uint4 v = xr[(size_t)s * 16 + q];
        float2 f0 = h2f2(v.x), f1 = h2f2(v.y), f2 = h2f2(v.z), f3 = h2f2(v.w);
        a[0] = fmaf(w, f0.x, a[0]); a[1] = fmaf(w, f0.y, a[1]);
        a[2] = fmaf(w, f1.x, a[2]); a[3] = fmaf(w, f1.y, a[3]);
        a[4] = fmaf(w, f2.x, a[4]); a[5] = fmaf(w, f2.y, a[5]);
        a[6] = fmaf(w, f3.x, a[6]); a[7] = fmaf(w, f3.y, a[7]);
    }
    *(float4*)&red[p * 128 + q * 8 + 0] = make_float4(a[0], a[1], a[2], a[3]);
    *(float4*)&red[p * 128 + q * 8 + 4] = make_float4(a[4], a[5], a[6], a[7]);
    __syncthreads();
    float sum = 0.f;
    #pragma unroll
    for (int pp = 0; pp < 8; ++pp) sum += red[pp * 128 + t];
    float v = sum + b1[t];
    h1[(size_t)d * 128 + t] = v > 0.f ? v : expm1f(v);   // ELU
}

// ---------- GEMM2 + fused logits2, fp16 output ----------
__global__ __launch_bounds__(128) void gemm2_kernel(const float* __restrict__ h1,
        const float* __restrict__ W2, const float* __restrict__ a_src,
        const float* __restrict__ a_dst, half_t* __restrict__ xp2h,
        float* __restrict__ al_s, float* __restrict__ al_d, int N) {
    __shared__ __align__(16) float ws[128 * 32];
    __shared__ __align__(16) float xst[128 * 68];
    int t = threadIdx.x;
    int row0 = blockIdx.x * 64;
    const float4* wsrc = (const float4*)W2;
    float4* wdst = (float4*)ws;
    #pragma unroll
    for (int ii = 0; ii < 8; ++ii) wdst[t + 128 * ii] = wsrc[t + 128 * ii];
    #pragma unroll
    for (int ii = 0; ii < 16; ++ii) {
        int idx = t + 128 * ii;
        int r = idx >> 5, kq = idx & 31;
        int n = row0 + r;
        float4 v = make_float4(0.f, 0.f, 0.f, 0.f);
        if (n < N) v = *(const float4*)&h1[(size_t)n * 128 + kq * 4];
        xst[(kq * 4 + 0) * 68 + r] = v.x;
        xst[(kq * 4 + 1) * 68 + r] = v.y;
        xst[(kq * 4 + 2) * 68 + r] = v.z;
        xst[(kq * 4 + 3) * 68 + r] = v.w;
    }
    __syncthreads();
    int cg = t & 7, rg = t >> 3;
    float acc[4][4] = {};
    #pragma unroll 4
    for (int k = 0; k < 128; ++k) {
        float4 wv = *(const float4*)&ws[k * 32 + cg * 4];
        float4 xv = *(const float4*)&xst[k * 68 + rg * 4];
        float xr[4] = {xv.x, xv.y, xv.z, xv.w};
        float wr[4] = {wv.x, wv.y, wv.z, wv.w};
        #pragma unroll
        for (int r = 0; r < 4; ++r)
            #pragma unroll
            for (int c = 0; c < 4; ++c)
                acc[r][c] = fmaf(xr[r], wr[c], acc[r][c]);
    }
    #pragma unroll
    for (int r = 0; r < 4; ++r) {
        int n = row0 + rg * 4 + r;
        if (n < N) {
            uint2 u = make_uint2(f2h2(acc[r][0], acc[r][1]), f2h2(acc[r][2], acc[r][3]));
            *(uint2*)&xp2h[(size_t)n * 32 + cg * 4] = u;
        }
    }
    float ps[4], pd[4];
    #pragma unroll
    for (int r = 0; r < 4; ++r) {
        float s = 0.f, dd = 0.f;
        #pragma unroll
        for (int c = 0; c < 4; ++c) {
            s  = fmaf(acc[r][c], a_src[cg * 4 + c], s);
            dd = fmaf(acc[r][c], a_dst[cg * 4 + c], dd);
        }
        ps[r] = s; pd[r] = dd;
    }
    #pragma unroll
    for (int m = 1; m < 8; m <<= 1) {
        #pragma unroll
        for (int r = 0; r < 4; ++r) { ps[r] += __shfl_xor(ps[r], m); pd[r] += __shfl_xor(pd[r], m); }
    }
    if (cg == 0) {
        #pragma unroll
        for (int r = 0; r < 4; ++r) {
            int n = row0 + rg * 4 + r;
            if (n < N) { al_s[n] = ps[r]; al_d[n] = pd[r]; }
        }
    }
}

// ---------- edge2: softmax + fp16 gather (4 lanes/edge, 32 edges in flight) ----------
__global__ __launch_bounds__(128) void edge2_kernel(const int* __restrict__ cnt,
        const int* __restrict__ adj, const float* __restrict__ al_s,
        const float* __restrict__ al_d, const half_t* __restrict__ xp2h,
        const float* __restrict__ b2v, float* __restrict__ out, int N) {
    __shared__ int srcs[CAP];
    __shared__ float ew[CAP];
    __shared__ __align__(16) float red[32 * 32];
    __shared__ float red2[128];
    __shared__ float wden[2];
    int d = blockIdx.x, t = threadIdx.x;
    int deg = cnt[d]; if (deg > CAP) deg = CAP;
    float ex = 0.f;
    if (t < deg) {
        int s = adj[(size_t)d * CAP + t];
        srcs[t] = s;
        ex = expf(lrelu(al_s[s] + al_d[d]));
    }
    float r = ex;
    #pragma unroll
    for (int m = 1; m < 64; m <<= 1) r += __shfl_xor(r, m);
    if ((t & 63) == 0) wden[t >> 6] = r;
    __syncthreads();
    float den = wden[0] + wden[1];
    if (t < deg) ew[t] = ex / (den + 1e-16f);
    __syncthreads();
    int q = t & 3, p = t >> 2;                // lane-group q owns channels 8q..8q+7
    float a[8] = {};
    const uint4* xr = (const uint4*)xp2h;     // row = 4 uint4
    for (int i = p; i < deg; i += 32) {
        int s = srcs[i];
        float w = ew[i];
        uint4 v = xr[(size_t)s * 4 + q];
        float2 f0 = h2f2(v.x), f1 = h2f2(v.y), f2 = h2f2(v.z), f3 = h2f2(v.w);
        a[0] = fmaf(w, f0.x, a[0]); a[1] = fmaf(w, f0.y, a[1]);
        a[2] = fmaf(w, f1.x, a[2]); a[3] = fmaf(w, f1.y, a[3]);
        a[4] = fmaf(w, f2.x, a[4]); a[5] = fmaf(w, f2.y, a[5]);
        a[6] = fmaf(w, f3.x, a[6]); a[7] = fmaf(w, f3.y, a[7]);
    }
    *(float4*)&red[p * 32 + q * 8 + 0] = make_float4(a[0], a[1], a[2], a[3]);
    *(float4*)&red[p * 32 + q * 8 + 4] = make_float4(a[4], a[5], a[6], a[7]);
    __syncthreads();
    int c = t & 31, g = t >> 5;
    float part = 0.f;
    #pragma unroll
    for (int k = 0; k < 8; ++k) part += red[(g * 8 + k) * 32 + c];
    red2[t] = part;
    __syncthreads();
    if (t < 32) {
        float s2 = red2[t] + red2[t + 32] + red2[t + 64] + red2[t + 96];
        out[(size_t)d * 32 + t] = s2 + b2v[t];
    }
}

extern "C" void kernel_launch(void* const* d_in, const int* in_sizes, int n_in,
                              void* d_out, int out_size, void* d_ws, size_t ws_size,
                              hipStream_t stream) {
    const float* x    = (const float*)d_in[0];
    const int*   ei   = (const int*)d_in[1];
    const float* W1   = (const float*)d_in[2];
    const float* a_s1 = (const float*)d_in[3];
    const float* a_d1 = (const float*)d_in[4];
    const float* b1   = (const float*)d_in[5];
    const float* W2   = (const float*)d_in[6];
    const float* a_s2 = (const float*)d_in[7];
    const float* a_d2 = (const float*)d_in[8];
    const float* b2   = (const float*)d_in[9];
    int N = in_sizes[0] / 128;
    int E = in_sizes[1] / 2;
    float* out = (float*)d_out;

    int shift = 0;
    while (((N - 1) >> shift) >= NB) shift++;

    char* wsb = (char*)d_ws;
    size_t off = 0;
    auto alloc = [&](size_t bytes) -> void* {
        void* p = wsb + off;
        off = (off + bytes + 255) & ~(size_t)255;
        return p;
    };
    int*    cnt      = (int*)   alloc((size_t)N * 4);
    int*    adj      = (int*)   alloc((size_t)N * CAP * 4);
    int*    partials = (int*)   alloc((size_t)GAB * NB * 4);
    int*    bin_base = (int*)   alloc((size_t)(NB + 1) * 4);
    half_t* xp1h     = (half_t*)alloc((size_t)N * 128 * 2);
    float*  al_s1    = (float*) alloc((size_t)N * 4 * 4);
    float*  al_d1    = (float*) alloc((size_t)N * 4 * 4);
    float*  h1       = (float*) alloc((size_t)N * 128 * 4);
    // aliases: binned (dead after k_fill) shares h1; layer-2 reuses layer-1 buffers
    int2*   binned   = (int2*)h1;      // (E+N)*8 = 13.2MB <= N*512 = 25.6MB
    half_t* xp2h     = xp1h;           // N*32*2 <= N*128*2
    float*  al_s2v   = al_s1;
    float*  al_d2v   = al_d1;

    k_count<<<GAB, 256, 0, stream>>>(ei, E, N, shift, partials, cnt);
    k_scan<<<1, 256, 0, stream>>>(partials, bin_base);
    k_bin<<<GAB, 256, 0, stream>>>(ei, E, N, shift, partials, binned);
    k_fill<<<NB * SUBS, 256, 0, stream>>>(binned, bin_base, cnt, adj);
    gemm1_kernel<<<(N + 31) / 32, 256, 0, stream>>>(x, W1, a_s1, a_d1, xp1h, al_s1, al_d1, N);
    edge1_kernel<<<N, 128, 0, stream>>>(cnt, adj, al_s1, al_d1, xp1h, b1, h1, N);
    gemm2_kernel<<<(N + 63) / 64, 128, 0, stream>>>(h1, W2, a_s2, a_d2, xp2h, al_s2v, al_d2v, N);
    edge2_kernel<<<N, 128, 0, stream>>>(cnt, adj, al_s2v, al_d2v, xp2h, b2, out, N);
}

// Round 5
// 321.598 us; speedup vs baseline: 1.4208x; 1.0080x over previous
//
#include <hip/hip_runtime.h>
#include <hip/hip_fp16.h>

#define NEG_SLOPE 0.2f
#define CAP 128     // max in-degree slots; in-degree ~ Poisson(33), P(deg>96) ~ 1e-19
#define NB  64      // coarse dst bins
#define GAB 192     // blocks for count/bin passes
#define SUBS 32     // blocks per bin in fill phase

typedef __half half_t;

__device__ __forceinline__ float lrelu(float x) { return x >= 0.f ? x : NEG_SLOPE * x; }

__device__ __forceinline__ float2 h2f2(unsigned int u) {
    union { unsigned int u; __half2 h; } v; v.u = u;
    return __half22float2(v.h);
}
__device__ __forceinline__ unsigned int f2h2(float a, float b) {
    union { unsigned int u; __half2 h; } v; v.h = __floats2half2_rn(a, b);
    return v.u;
}

// int64 edge_index detection: odd int32 words of first 64 entries are all zero
__device__ __forceinline__ bool edge_is64(const int* __restrict__ ei, int E) {
    int t = threadIdx.x & 63;
    int idx = 2 * t + 1; if (idx >= 2 * E) idx = 2 * E - 1;
    unsigned long long b = __ballot(ei[idx] != 0);
    return b == 0ULL;
}

__device__ __forceinline__ void load_edge(const int* __restrict__ ei, int E, int i,
                                          bool is64, int& s, int& d) {
    if (i < E) {
        if (is64) { const long long* e = (const long long*)ei; s = (int)e[i]; d = (int)e[E + i]; }
        else      { s = ei[i]; d = ei[E + i]; }
    } else { s = d = i - E; }            // PyG add_self_loops
}

// ---------- phase 1: per-block per-bin counts (+ zero cnt for k_fill) ----------
__global__ __launch_bounds__(256) void k_count(const int* __restrict__ ei,
        int E, int N, int shift, int* __restrict__ partials, int* __restrict__ cnt) {
    __shared__ int cnts[NB];
    int t = threadIdx.x, b = blockIdx.x;
    if (t < NB) cnts[t] = 0;
    bool is64 = edge_is64(ei, E);
    for (int i = b * 256 + t; i < N; i += GAB * 256) cnt[i] = 0;
    __syncthreads();
    int tot = E + N;
    for (int i = b * 256 + t; i < tot; i += GAB * 256) {
        int s, d; load_edge(ei, E, i, is64, s, d);
        atomicAdd(&cnts[d >> shift], 1);
    }
    __syncthreads();
    if (t < NB) partials[b * NB + t] = cnts[t];
}

// ---------- phase 2: scan -> per-(block,bin) write offsets + bin bases ----------
__global__ __launch_bounds__(256) void k_scan(int* __restrict__ partials,
                                              int* __restrict__ bin_base) {
    __shared__ int lp[GAB * NB];    // 48KB
    __shared__ int tot[NB], base[NB];
    int t = threadIdx.x;
    for (int i = t; i < GAB * NB; i += 256) lp[i] = partials[i];
    __syncthreads();
    if (t < NB) {
        int run = 0;
        for (int b = 0; b < GAB; ++b) { int v = lp[b * NB + t]; lp[b * NB + t] = run; run += v; }
        tot[t] = run;
    }
    __syncthreads();
    if (t == 0) {
        int run = 0;
        for (int i = 0; i < NB; ++i) { base[i] = run; run += tot[i]; }
    }
    __syncthreads();
    if (t < NB) bin_base[t] = base[t];
    if (t == 0) bin_base[NB] = base[NB - 1] + tot[NB - 1];
    for (int i = t; i < GAB * NB; i += 256) partials[i] = lp[i] + base[i & (NB - 1)];
}

// ---------- phase 3: scatter edges into dst bins (LDS cursors) ----------
__global__ __launch_bounds__(256) void k_bin(const int* __restrict__ ei,
        int E, int N, int shift, const int* __restrict__ offsets, int2* __restrict__ binned) {
    __shared__ int cur[NB];
    int t = threadIdx.x, b = blockIdx.x;
    if (t < NB) cur[t] = offsets[b * NB + t];
    bool is64 = edge_is64(ei, E);
    __syncthreads();
    int tot = E + N;
    for (int i = b * 256 + t; i < tot; i += GAB * 256) {
        int s, d; load_edge(ei, E, i, is64, s, d);
        int pos = atomicAdd(&cur[d >> shift], 1);
        binned[pos] = make_int2(s, d);
    }
}

// ---------- phase 4: fill adj; bin -> fixed blockIdx%NB residue => XCD-local L2 ----------
__global__ __launch_bounds__(256) void k_fill(const int2* __restrict__ binned,
        const int* __restrict__ bin_base, int* __restrict__ cnt, int* __restrict__ adj) {
    int t = threadIdx.x;
    int bin = blockIdx.x & (NB - 1);
    int sub = blockIdx.x >> 6;
    int lo = bin_base[bin], hi = bin_base[bin + 1];
    for (int i = lo + sub * 256 + t; i < hi; i += SUBS * 256) {
        int2 e = binned[i];
        int pos = atomicAdd(&cnt[e.y], 1);
        if (pos < CAP) adj[(size_t)e.y * CAP + pos] = e.x;
    }
}

// ---------- GEMM1 + fused logits1, fp16 output ----------
__global__ __launch_bounds__(256) void gemm1_kernel(const float* __restrict__ x,
        const float* __restrict__ W1, const float* __restrict__ a_src,
        const float* __restrict__ a_dst, half_t* __restrict__ xp1h,
        float* __restrict__ al_s, float* __restrict__ al_d, int N) {
    __shared__ __align__(16) float ws[64 * 128];
    __shared__ __align__(16) float xst[128 * 36];
    int t = threadIdx.x;
    int row0 = blockIdx.x * 32;
    #pragma unroll
    for (int ii = 0; ii < 4; ++ii) {
        int idx = t + 256 * ii;
        int r = idx >> 5, kq = idx & 31;
        int n = row0 + r;
        float4 v = make_float4(0.f, 0.f, 0.f, 0.f);
        if (n < N) v = *(const float4*)&x[(size_t)n * 128 + kq * 4];
        xst[(kq * 4 + 0) * 36 + r] = v.x;
        xst[(kq * 4 + 1) * 36 + r] = v.y;
        xst[(kq * 4 + 2) * 36 + r] = v.z;
        xst[(kq * 4 + 3) * 36 + r] = v.w;
    }
    int cg = t & 31, rg = t >> 5;
    float acc[4][4] = {};
    for (int half = 0; half < 2; ++half) {
        __syncthreads();
        const float4* wsrc = (const float4*)(W1 + half * 64 * 128);
        float4* wdst = (float4*)ws;
        #pragma unroll
        for (int ii = 0; ii < 8; ++ii) wdst[t + 256 * ii] = wsrc[t + 256 * ii];
        __syncthreads();
        #pragma unroll 4
        for (int k = 0; k < 64; ++k) {
            float4 wv = *(const float4*)&ws[k * 128 + cg * 4];
            float4 xv = *(const float4*)&xst[(half * 64 + k) * 36 + rg * 4];
            float xr[4] = {xv.x, xv.y, xv.z, xv.w};
            float wr[4] = {wv.x, wv.y, wv.z, wv.w};
            #pragma unroll
            for (int r = 0; r < 4; ++r)
                #pragma unroll
                for (int c = 0; c < 4; ++c)
                    acc[r][c] = fmaf(xr[r], wr[c], acc[r][c]);
        }
    }
    #pragma unroll
    for (int r = 0; r < 4; ++r) {
        int n = row0 + rg * 4 + r;
        if (n < N) {
            uint2 u = make_uint2(f2h2(acc[r][0], acc[r][1]), f2h2(acc[r][2], acc[r][3]));
            *(uint2*)&xp1h[(size_t)n * 128 + cg * 4] = u;
        }
    }
    float ps[4], pd[4];
    #pragma unroll
    for (int r = 0; r < 4; ++r) {
        float s = 0.f, dd = 0.f;
        #pragma unroll
        for (int c = 0; c < 4; ++c) {
            s  = fmaf(acc[r][c], a_src[cg * 4 + c], s);
            dd = fmaf(acc[r][c], a_dst[cg * 4 + c], dd);
        }
        ps[r] = s; pd[r] = dd;
    }
    #pragma unroll
    for (int m = 1; m < 8; m <<= 1) {
        #pragma unroll
        for (int r = 0; r < 4; ++r) { ps[r] += __shfl_xor(ps[r], m); pd[r] += __shfl_xor(pd[r], m); }
    }
    if ((cg & 7) == 0) {
        int head = cg >> 3;
        #pragma unroll
        for (int r = 0; r < 4; ++r) {
            int n = row0 + rg * 4 + r;
            if (n < N) { al_s[n * 4 + head] = ps[r]; al_d[n * 4 + head] = pd[r]; }
        }
    }
}

// ---------- edge1: softmax + 4-deep unrolled fp16 gather + fused gemm2/logits2 ----------
__global__ __launch_bounds__(128) void edge1_kernel(const int* __restrict__ cnt,
        const int* __restrict__ adj, const float* __restrict__ al_s,
        const float* __restrict__ al_d, const half_t* __restrict__ xp1h,
        const float* __restrict__ b1, const float* __restrict__ W2,
        const float* __restrict__ a_s2, const float* __restrict__ a_d2,
        half_t* __restrict__ xp2h, float* __restrict__ al_s2, float* __restrict__ al_d2,
        int N) {
    __shared__ int srcs[CAP];
    __shared__ float ew[CAP * 4];
    __shared__ __align__(16) float red[8 * 128];
    __shared__ float h1s[128];
    __shared__ float4 wden[2];
    int d = blockIdx.x, t = threadIdx.x;
    int deg = cnt[d]; if (deg > CAP) deg = CAP;
    float4 ex = make_float4(0.f, 0.f, 0.f, 0.f);
    if (t < deg) {
        int s = adj[(size_t)d * CAP + t];
        srcs[t] = s;
        float4 as = *(const float4*)&al_s[s * 4];
        float4 ad = *(const float4*)&al_d[d * 4];
        ex.x = expf(lrelu(as.x + ad.x));
        ex.y = expf(lrelu(as.y + ad.y));
        ex.z = expf(lrelu(as.z + ad.z));
        ex.w = expf(lrelu(as.w + ad.w));
    }
    float4 r = ex;
    #pragma unroll
    for (int m = 1; m < 64; m <<= 1) {
        r.x += __shfl_xor(r.x, m); r.y += __shfl_xor(r.y, m);
        r.z += __shfl_xor(r.z, m); r.w += __shfl_xor(r.w, m);
    }
    if ((t & 63) == 0) wden[t >> 6] = r;
    __syncthreads();
    float4 den = wden[0], dn1 = wden[1];
    den.x += dn1.x; den.y += dn1.y; den.z += dn1.z; den.w += dn1.w;
    if (t < deg) {
        float4 al;
        al.x = ex.x / (den.x + 1e-16f); al.y = ex.y / (den.y + 1e-16f);
        al.z = ex.z / (den.z + 1e-16f); al.w = ex.w / (den.w + 1e-16f);
        *(float4*)&ew[t * 4] = al;
    }
    __syncthreads();
    // gather: 16 lanes/edge, 32 edges per round (4 outstanding loads/thread)
    int q = t & 15, p = t >> 4, h = q >> 2;
    float a[8] = {};
    const uint4* xr = (const uint4*)xp1h;     // row = 16 uint4
    int rounds = (deg + 31) >> 5;
    for (int rr = 0; rr < rounds; ++rr) {
        int i0 = rr * 32 + p;
        int i1 = i0 + 8, i2 = i0 + 16, i3 = i0 + 24;
        uint4 v0, v1, v2, v3;
        float w0 = 0.f, w1 = 0.f, w2 = 0.f, w3 = 0.f;
        if (i0 < deg) { v0 = xr[(size_t)srcs[i0] * 16 + q]; w0 = ew[i0 * 4 + h]; }
        if (i1 < deg) { v1 = xr[(size_t)srcs[i1] * 16 + q]; w1 = ew[i1 * 4 + h]; }
        if (i2 < deg) { v2 = xr[(size_t)srcs[i2] * 16 + q]; w2 = ew[i2 * 4 + h]; }
        if (i3 < deg) { v3 = xr[(size_t)srcs[i3] * 16 + q]; w3 = ew[i3 * 4 + h]; }
        if (i0 < deg) {
            float2 f0 = h2f2(v0.x), f1 = h2f2(v0.y), f2 = h2f2(v0.z), f3 = h2f2(v0.w);
            a[0] = fmaf(w0, f0.x, a[0]); a[1] = fmaf(w0, f0.y, a[1]);
            a[2] = fmaf(w0, f1.x, a[2]); a[3] = fmaf(w0, f1.y, a[3]);
            a[4] = fmaf(w0, f2.x, a[4]); a[5] = fmaf(w0, f2.y, a[5]);
            a[6] = fmaf(w0, f3.x, a[6]); a[7] = fmaf(w0, f3.y, a[7]);
        }
        if (i1 < deg) {
            float2 f0 = h2f2(v1.x), f1 = h2f2(v1.y), f2 = h2f2(v1.z), f3 = h2f2(v1.w);
            a[0] = fmaf(w1, f0.x, a[0]); a[1] = fmaf(w1, f0.y, a[1]);
            a[2] = fmaf(w1, f1.x, a[2]); a[3] = fmaf(w1, f1.y, a[3]);
            a[4] = fmaf(w1, f2.x, a[4]); a[5] = fmaf(w1, f2.y, a[5]);
            a[6] = fmaf(w1, f3.x, a[6]); a[7] = fmaf(w1, f3.y, a[7]);
        }
        if (i2 < deg) {
            float2 f0 = h2f2(v2.x), f1 = h2f2(v2.y), f2 = h2f2(v2.z), f3 = h2f2(v2.w);
            a[0] = fmaf(w2, f0.x, a[0]); a[1] = fmaf(w2, f0.y, a[1]);
            a[2] = fmaf(w2, f1.x, a[2]); a[3] = fmaf(w2, f1.y, a[3]);
            a[4] = fmaf(w2, f2.x, a[4]); a[5] = fmaf(w2, f2.y, a[5]);
            a[6] = fmaf(w2, f3.x, a[6]); a[7] = fmaf(w2, f3.y, a[7]);
        }
        if (i3 < deg) {
            float2 f0 = h2f2(v3.x), f1 = h2f2(v3.y), f2 = h2f2(v3.z), f3 = h2f2(v3.w);
            a[0] = fmaf(w3, f0.x, a[0]); a[1] = fmaf(w3, f0.y, a[1]);
            a[2] = fmaf(w3, f1.x, a[2]); a[3] = fmaf(w3, f1.y, a[3]);
            a[4] = fmaf(w3, f2.x, a[4]); a[5] = fmaf(w3, f2.y, a[5]);
            a[6] = fmaf(w3, f3.x, a[6]); a[7] = fmaf(w3, f3.y, a[7]);
        }
    }
    *(float4*)&red[p * 128 + q * 8 + 0] = make_float4(a[0], a[1], a[2], a[3]);
    *(float4*)&red[p * 128 + q * 8 + 4] = make_float4(a[4], a[5], a[6], a[7]);
    __syncthreads();
    float sum = 0.f;
    #pragma unroll
    for (int pp = 0; pp < 8; ++pp) sum += red[pp * 128 + t];
    float v = sum + b1[t];
    h1s[t] = v > 0.f ? v : expm1f(v);   // ELU; h1 row lives only in LDS now
    __syncthreads();
    // fused gemm2: xp2[d] = h1row @ W2 (128x32), K split across 4 groups
    int c = t & 31, g = t >> 5;
    float part = 0.f;
    #pragma unroll 8
    for (int k = 0; k < 32; ++k)
        part = fmaf(h1s[g * 32 + k], W2[(size_t)(g * 32 + k) * 32 + c], part);
    red[t] = part;
    __syncthreads();
    if (t < 32) {
        float xv = red[t] + red[t + 32] + red[t + 64] + red[t + 96];
        xp2h[(size_t)d * 32 + t] = __float2half(xv);
        float ps = xv * a_s2[t], pd = xv * a_d2[t];
        #pragma unroll
        for (int m = 1; m < 32; m <<= 1) { ps += __shfl_xor(ps, m); pd += __shfl_xor(pd, m); }
        if (t == 0) { al_s2[d] = ps; al_d2[d] = pd; }
    }
}

// ---------- edge2: softmax + fp16 gather (2-deep unroll) -> out [N,32] ----------
__global__ __launch_bounds__(128) void edge2_kernel(const int* __restrict__ cnt,
        const int* __restrict__ adj, const float* __restrict__ al_s,
        const float* __restrict__ al_d, const half_t* __restrict__ xp2h,
        const float* __restrict__ b2v, float* __restrict__ out, int N) {
    __shared__ int srcs[CAP];
    __shared__ float ew[CAP];
    __shared__ __align__(16) float red[32 * 32];
    __shared__ float red2[128];
    __shared__ float wden[2];
    int d = blockIdx.x, t = threadIdx.x;
    int deg = cnt[d]; if (deg > CAP) deg = CAP;
    float ex = 0.f;
    if (t < deg) {
        int s = adj[(size_t)d * CAP + t];
        srcs[t] = s;
        ex = expf(lrelu(al_s[s] + al_d[d]));
    }
    float r = ex;
    #pragma unroll
    for (int m = 1; m < 64; m <<= 1) r += __shfl_xor(r, m);
    if ((t & 63) == 0) wden[t >> 6] = r;
    __syncthreads();
    float den = wden[0] + wden[1];
    if (t < deg) ew[t] = ex / (den + 1e-16f);
    __syncthreads();
    int q = t & 3, p = t >> 2;                // 4 lanes/edge, 32 edges/round-half
    float a[8] = {};
    const uint4* xr = (const uint4*)xp2h;     // row = 4 uint4
    int rounds = (deg + 63) >> 6;
    for (int rr = 0; rr < rounds; ++rr) {
        int i0 = rr * 64 + p, i1 = i0 + 32;
        uint4 v0, v1; float w0 = 0.f, w1 = 0.f;
        if (i0 < deg) { v0 = xr[(size_t)srcs[i0] * 4 + q]; w0 = ew[i0]; }
        if (i1 < deg) { v1 = xr[(size_t)srcs[i1] * 4 + q]; w1 = ew[i1]; }
        if (i0 < deg) {
            float2 f0 = h2f2(v0.x), f1 = h2f2(v0.y), f2 = h2f2(v0.z), f3 = h2f2(v0.w);
            a[0] = fmaf(w0, f0.x, a[0]); a[1] = fmaf(w0, f0.y, a[1]);
            a[2] = fmaf(w0, f1.x, a[2]); a[3] = fmaf(w0, f1.y, a[3]);
            a[4] = fmaf(w0, f2.x, a[4]); a[5] = fmaf(w0, f2.y, a[5]);
            a[6] = fmaf(w0, f3.x, a[6]); a[7] = fmaf(w0, f3.y, a[7]);
        }
        if (i1 < deg) {
            float2 f0 = h2f2(v1.x), f1 = h2f2(v1.y), f2 = h2f2(v1.z), f3 = h2f2(v1.w);
            a[0] = fmaf(w1, f0.x, a[0]); a[1] = fmaf(w1, f0.y, a[1]);
            a[2] = fmaf(w1, f1.x, a[2]); a[3] = fmaf(w1, f1.y, a[3]);
            a[4] = fmaf(w1, f2.x, a[4]); a[5] = fmaf(w1, f2.y, a[5]);
            a[6] = fmaf(w1, f3.x, a[6]); a[7] = fmaf(w1, f3.y, a[7]);
        }
    }
    *(float4*)&red[p * 32 + q * 8 + 0] = make_float4(a[0], a[1], a[2], a[3]);
    *(float4*)&red[p * 32 + q * 8 + 4] = make_float4(a[4], a[5], a[6], a[7]);
    __syncthreads();
    int c = t & 31, g = t >> 5;
    float part = 0.f;
    #pragma unroll
    for (int k = 0; k < 8; ++k) part += red[(g * 8 + k) * 32 + c];
    red2[t] = part;
    __syncthreads();
    if (t < 32) {
        float s2 = red2[t] + red2[t + 32] + red2[t + 64] + red2[t + 96];
        out[(size_t)d * 32 + t] = s2 + b2v[t];
    }
}

extern "C" void kernel_launch(void* const* d_in, const int* in_sizes, int n_in,
                              void* d_out, int out_size, void* d_ws, size_t ws_size,
                              hipStream_t stream) {
    const float* x    = (const float*)d_in[0];
    const int*   ei   = (const int*)d_in[1];
    const float* W1   = (const float*)d_in[2];
    const float* a_s1 = (const float*)d_in[3];
    const float* a_d1 = (const float*)d_in[4];
    const float* b1   = (const float*)d_in[5];
    const float* W2   = (const float*)d_in[6];
    const float* a_s2 = (const float*)d_in[7];
    const float* a_d2 = (const float*)d_in[8];
    const float* b2   = (const float*)d_in[9];
    int N = in_sizes[0] / 128;
    int E = in_sizes[1] / 2;
    float* out = (float*)d_out;

    int shift = 0;
    while (((N - 1) >> shift) >= NB) shift++;

    char* wsb = (char*)d_ws;
    size_t off = 0;
    auto alloc = [&](size_t bytes) -> void* {
        void* p = wsb + off;
        off = (off + bytes + 255) & ~(size_t)255;
        return p;
    };
    int*    cnt      = (int*)   alloc((size_t)N * 4);
    int*    adj      = (int*)   alloc((size_t)N * CAP * 4);
    int*    partials = (int*)   alloc((size_t)GAB * NB * 4);
    int*    bin_base = (int*)   alloc((size_t)(NB + 1) * 4);
    int2*   binned   = (int2*)  alloc((size_t)(E + N) * 8);
    half_t* xp1h     = (half_t*)alloc((size_t)N * 128 * 2);
    float*  al_s1    = (float*) alloc((size_t)N * 4 * 4);
    float*  al_d1    = (float*) alloc((size_t)N * 4 * 4);
    half_t* xp2h     = (half_t*)alloc((size_t)N * 32 * 2);
    float*  al_s2    = (float*) alloc((size_t)N * 4);
    float*  al_d2    = (float*) alloc((size_t)N * 4);

    k_count<<<GAB, 256, 0, stream>>>(ei, E, N, shift, partials, cnt);
    k_scan<<<1, 256, 0, stream>>>(partials, bin_base);
    k_bin<<<GAB, 256, 0, stream>>>(ei, E, N, shift, partials, binned);
    k_fill<<<NB * SUBS, 256, 0, stream>>>(binned, bin_base, cnt, adj);
    gemm1_kernel<<<(N + 31) / 32, 256, 0, stream>>>(x, W1, a_s1, a_d1, xp1h, al_s1, al_d1, N);
    edge1_kernel<<<N, 128, 0, stream>>>(cnt, adj, al_s1, al_d1, xp1h, b1,
                                        W2, a_s2, a_d2, xp2h, al_s2, al_d2, N);
    edge2_kernel<<<N, 128, 0, stream>>>(cnt, adj, al_s2, al_d2, xp2h, b2, out, N);
}

// Round 6
// 312.471 us; speedup vs baseline: 1.4623x; 1.0292x over previous
//
#include <hip/hip_runtime.h>
#include <hip/hip_fp16.h>

#define NEG_SLOPE 0.2f
#define CAP 128     // max in-degree slots; in-degree ~ Poisson(33), P(deg>96) ~ 1e-19
#define NB  64      // coarse dst bins
#define GAB 192     // blocks for count/bin passes
#define SUBS 32     // blocks per bin in fill phase

typedef __half half_t;

__device__ __forceinline__ float lrelu(float x) { return x >= 0.f ? x : NEG_SLOPE * x; }

__device__ __forceinline__ float2 h2f2(unsigned int u) {
    union { unsigned int u; __half2 h; } v; v.u = u;
    return __half22float2(v.h);
}
__device__ __forceinline__ unsigned int f2h2(float a, float b) {
    union { unsigned int u; __half2 h; } v; v.h = __floats2half2_rn(a, b);
    return v.u;
}

// int64 edge_index detection: odd int32 words of first 64 entries are all zero
__device__ __forceinline__ bool edge_is64(const int* __restrict__ ei, int E) {
    int t = threadIdx.x & 63;
    int idx = 2 * t + 1; if (idx >= 2 * E) idx = 2 * E - 1;
    unsigned long long b = __ballot(ei[idx] != 0);
    return b == 0ULL;
}

__device__ __forceinline__ void load_edge(const int* __restrict__ ei, int E, int i,
                                          bool is64, int& s, int& d) {
    if (i < E) {
        if (is64) { const long long* e = (const long long*)ei; s = (int)e[i]; d = (int)e[E + i]; }
        else      { s = ei[i]; d = ei[E + i]; }
    } else { s = d = i - E; }            // PyG add_self_loops
}

// ---------- phase 1: per-block per-bin counts (+ zero cnt for k_fill) ----------
__global__ __launch_bounds__(256) void k_count(const int* __restrict__ ei,
        int E, int N, int shift, int* __restrict__ partials, int* __restrict__ cnt) {
    __shared__ int cnts[NB];
    int t = threadIdx.x, b = blockIdx.x;
    if (t < NB) cnts[t] = 0;
    bool is64 = edge_is64(ei, E);
    for (int i = b * 256 + t; i < N; i += GAB * 256) cnt[i] = 0;
    __syncthreads();
    int tot = E + N;
    for (int i = b * 256 + t; i < tot; i += GAB * 256) {
        int s, d; load_edge(ei, E, i, is64, s, d);
        atomicAdd(&cnts[d >> shift], 1);
    }
    __syncthreads();
    if (t < NB) partials[b * NB + t] = cnts[t];
}

// ---------- phase 2: scan -> per-(block,bin) write offsets + bin bases ----------
__global__ __launch_bounds__(256) void k_scan(int* __restrict__ partials,
                                              int* __restrict__ bin_base) {
    __shared__ int lp[GAB * NB];    // 48KB
    __shared__ int tot[NB], base[NB];
    int t = threadIdx.x;
    for (int i = t; i < GAB * NB; i += 256) lp[i] = partials[i];
    __syncthreads();
    if (t < NB) {
        int run = 0;
        for (int b = 0; b < GAB; ++b) { int v = lp[b * NB + t]; lp[b * NB + t] = run; run += v; }
        tot[t] = run;
    }
    __syncthreads();
    if (t == 0) {
        int run = 0;
        for (int i = 0; i < NB; ++i) { base[i] = run; run += tot[i]; }
    }
    __syncthreads();
    if (t < NB) bin_base[t] = base[t];
    if (t == 0) bin_base[NB] = base[NB - 1] + tot[NB - 1];
    for (int i = t; i < GAB * NB; i += 256) partials[i] = lp[i] + base[i & (NB - 1)];
}

// ---------- phase 3: scatter edges into dst bins (LDS cursors) ----------
__global__ __launch_bounds__(256) void k_bin(const int* __restrict__ ei,
        int E, int N, int shift, const int* __restrict__ offsets, int2* __restrict__ binned) {
    __shared__ int cur[NB];
    int t = threadIdx.x, b = blockIdx.x;
    if (t < NB) cur[t] = offsets[b * NB + t];
    bool is64 = edge_is64(ei, E);
    __syncthreads();
    int tot = E + N;
    for (int i = b * 256 + t; i < tot; i += GAB * 256) {
        int s, d; load_edge(ei, E, i, is64, s, d);
        int pos = atomicAdd(&cur[d >> shift], 1);
        binned[pos] = make_int2(s, d);
    }
}

// ---------- phase 4: fill adj; bin -> fixed blockIdx%NB residue => XCD-local L2 ----------
__global__ __launch_bounds__(256) void k_fill(const int2* __restrict__ binned,
        const int* __restrict__ bin_base, int* __restrict__ cnt, int* __restrict__ adj) {
    int t = threadIdx.x;
    int bin = blockIdx.x & (NB - 1);
    int sub = blockIdx.x >> 6;
    int lo = bin_base[bin], hi = bin_base[bin + 1];
    for (int i = lo + sub * 256 + t; i < hi; i += SUBS * 256) {
        int2 e = binned[i];
        int pos = atomicAdd(&cnt[e.y], 1);
        if (pos < CAP) adj[(size_t)e.y * CAP + pos] = e.x;
    }
}

// ---------- GEMM1 + fused logits1, fp16 output (+ zero row N) ----------
__global__ __launch_bounds__(256) void gemm1_kernel(const float* __restrict__ x,
        const float* __restrict__ W1, const float* __restrict__ a_src,
        const float* __restrict__ a_dst, half_t* __restrict__ xp1h,
        float* __restrict__ al_s, float* __restrict__ al_d, int N) {
    __shared__ __align__(16) float ws[64 * 128];
    __shared__ __align__(16) float xst[128 * 36];
    int t = threadIdx.x;
    int row0 = blockIdx.x * 32;
    if (blockIdx.x == 0 && t < 16)     // zero row N for padded gathers
        ((uint4*)(xp1h + (size_t)N * 128))[t] = make_uint4(0, 0, 0, 0);
    #pragma unroll
    for (int ii = 0; ii < 4; ++ii) {
        int idx = t + 256 * ii;
        int r = idx >> 5, kq = idx & 31;
        int n = row0 + r;
        float4 v = make_float4(0.f, 0.f, 0.f, 0.f);
        if (n < N) v = *(const float4*)&x[(size_t)n * 128 + kq * 4];
        xst[(kq * 4 + 0) * 36 + r] = v.x;
        xst[(kq * 4 + 1) * 36 + r] = v.y;
        xst[(kq * 4 + 2) * 36 + r] = v.z;
        xst[(kq * 4 + 3) * 36 + r] = v.w;
    }
    int cg = t & 31, rg = t >> 5;
    float acc[4][4] = {};
    for (int half = 0; half < 2; ++half) {
        __syncthreads();
        const float4* wsrc = (const float4*)(W1 + half * 64 * 128);
        float4* wdst = (float4*)ws;
        #pragma unroll
        for (int ii = 0; ii < 8; ++ii) wdst[t + 256 * ii] = wsrc[t + 256 * ii];
        __syncthreads();
        #pragma unroll 4
        for (int k = 0; k < 64; ++k) {
            float4 wv = *(const float4*)&ws[k * 128 + cg * 4];
            float4 xv = *(const float4*)&xst[(half * 64 + k) * 36 + rg * 4];
            float xr[4] = {xv.x, xv.y, xv.z, xv.w};
            float wr[4] = {wv.x, wv.y, wv.z, wv.w};
            #pragma unroll
            for (int r = 0; r < 4; ++r)
                #pragma unroll
                for (int c = 0; c < 4; ++c)
                    acc[r][c] = fmaf(xr[r], wr[c], acc[r][c]);
        }
    }
    #pragma unroll
    for (int r = 0; r < 4; ++r) {
        int n = row0 + rg * 4 + r;
        if (n < N) {
            uint2 u = make_uint2(f2h2(acc[r][0], acc[r][1]), f2h2(acc[r][2], acc[r][3]));
            *(uint2*)&xp1h[(size_t)n * 128 + cg * 4] = u;
        }
    }
    float ps[4], pd[4];
    #pragma unroll
    for (int r = 0; r < 4; ++r) {
        float s = 0.f, dd = 0.f;
        #pragma unroll
        for (int c = 0; c < 4; ++c) {
            s  = fmaf(acc[r][c], a_src[cg * 4 + c], s);
            dd = fmaf(acc[r][c], a_dst[cg * 4 + c], dd);
        }
        ps[r] = s; pd[r] = dd;
    }
    #pragma unroll
    for (int m = 1; m < 8; m <<= 1) {
        #pragma unroll
        for (int r = 0; r < 4; ++r) { ps[r] += __shfl_xor(ps[r], m); pd[r] += __shfl_xor(pd[r], m); }
    }
    if ((cg & 7) == 0) {
        int head = cg >> 3;
        #pragma unroll
        for (int r = 0; r < 4; ++r) {
            int n = row0 + rg * 4 + r;
            if (n < N) { al_s[n * 4 + head] = ps[r]; al_d[n * 4 + head] = pd[r]; }
        }
    }
}

// ---------- edge1: softmax + branch-free padded 4-deep gather + fused gemm2/logits2 ----------
__global__ __launch_bounds__(128) void edge1_kernel(const int* __restrict__ cnt,
        const int* __restrict__ adj, const float* __restrict__ al_s,
        const float* __restrict__ al_d, const half_t* __restrict__ xp1h,
        const float* __restrict__ b1, const float* __restrict__ W2,
        const float* __restrict__ a_s2, const float* __restrict__ a_d2,
        half_t* __restrict__ xp2h, float* __restrict__ al_s2, float* __restrict__ al_d2,
        int N) {
    __shared__ int srcs[CAP];
    __shared__ float ew[CAP * 4];
    __shared__ __align__(16) float red[8 * 128];
    __shared__ float h1s[128];
    __shared__ float4 wden[2];
    int d = blockIdx.x, t = threadIdx.x;
    int deg = cnt[d]; if (deg > CAP) deg = CAP;
    float4 ex = make_float4(0.f, 0.f, 0.f, 0.f);
    int s = N;                              // pad slots gather the zero row
    if (t < deg) {
        s = adj[(size_t)d * CAP + t];
        float4 as = *(const float4*)&al_s[s * 4];
        float4 ad = *(const float4*)&al_d[d * 4];
        ex.x = expf(lrelu(as.x + ad.x));
        ex.y = expf(lrelu(as.y + ad.y));
        ex.z = expf(lrelu(as.z + ad.z));
        ex.w = expf(lrelu(as.w + ad.w));
    }
    srcs[t] = s;
    float4 r = ex;
    #pragma unroll
    for (int m = 1; m < 64; m <<= 1) {
        r.x += __shfl_xor(r.x, m); r.y += __shfl_xor(r.y, m);
        r.z += __shfl_xor(r.z, m); r.w += __shfl_xor(r.w, m);
    }
    if ((t & 63) == 0) wden[t >> 6] = r;
    __syncthreads();
    float4 den = wden[0], dn1 = wden[1];
    den.x += dn1.x; den.y += dn1.y; den.z += dn1.z; den.w += dn1.w;
    float4 al = make_float4(0.f, 0.f, 0.f, 0.f);   // pad slots get weight 0
    if (t < deg) {
        al.x = ex.x / (den.x + 1e-16f); al.y = ex.y / (den.y + 1e-16f);
        al.z = ex.z / (den.z + 1e-16f); al.w = ex.w / (den.w + 1e-16f);
    }
    *(float4*)&ew[t * 4] = al;
    __syncthreads();
    // gather: 16 lanes/edge, 32 edges/round, 4 unconditional loads/thread/round
    int q = t & 15, p = t >> 4, h = q >> 2;
    float a[8] = {};
    const uint4* xr = (const uint4*)xp1h;     // row = 16 uint4
    int degp = (deg + 31) & ~31;
    for (int rr = 0; rr < degp; rr += 32) {
        int i0 = rr + p, i1 = i0 + 8, i2 = i0 + 16, i3 = i0 + 24;
        int s0 = srcs[i0], s1 = srcs[i1], s2 = srcs[i2], s3 = srcs[i3];
        uint4 v0 = xr[(size_t)s0 * 16 + q];
        uint4 v1 = xr[(size_t)s1 * 16 + q];
        uint4 v2 = xr[(size_t)s2 * 16 + q];
        uint4 v3 = xr[(size_t)s3 * 16 + q];
        float w0 = ew[i0 * 4 + h], w1 = ew[i1 * 4 + h];
        float w2 = ew[i2 * 4 + h], w3 = ew[i3 * 4 + h];
        {
            float2 f0 = h2f2(v0.x), f1 = h2f2(v0.y), f2 = h2f2(v0.z), f3 = h2f2(v0.w);
            a[0] = fmaf(w0, f0.x, a[0]); a[1] = fmaf(w0, f0.y, a[1]);
            a[2] = fmaf(w0, f1.x, a[2]); a[3] = fmaf(w0, f1.y, a[3]);
            a[4] = fmaf(w0, f2.x, a[4]); a[5] = fmaf(w0, f2.y, a[5]);
            a[6] = fmaf(w0, f3.x, a[6]); a[7] = fmaf(w0, f3.y, a[7]);
        }
        {
            float2 f0 = h2f2(v1.x), f1 = h2f2(v1.y), f2 = h2f2(v1.z), f3 = h2f2(v1.w);
            a[0] = fmaf(w1, f0.x, a[0]); a[1] = fmaf(w1, f0.y, a[1]);
            a[2] = fmaf(w1, f1.x, a[2]); a[3] = fmaf(w1, f1.y, a[3]);
            a[4] = fmaf(w1, f2.x, a[4]); a[5] = fmaf(w1, f2.y, a[5]);
            a[6] = fmaf(w1, f3.x, a[6]); a[7] = fmaf(w1, f3.y, a[7]);
        }
        {
            float2 f0 = h2f2(v2.x), f1 = h2f2(v2.y), f2 = h2f2(v2.z), f3 = h2f2(v2.w);
            a[0] = fmaf(w2, f0.x, a[0]); a[1] = fmaf(w2, f0.y, a[1]);
            a[2] = fmaf(w2, f1.x, a[2]); a[3] = fmaf(w2, f1.y, a[3]);
            a[4] = fmaf(w2, f2.x, a[4]); a[5] = fmaf(w2, f2.y, a[5]);
            a[6] = fmaf(w2, f3.x, a[6]); a[7] = fmaf(w2, f3.y, a[7]);
        }
        {
            float2 f0 = h2f2(v3.x), f1 = h2f2(v3.y), f2 = h2f2(v3.z), f3 = h2f2(v3.w);
            a[0] = fmaf(w3, f0.x, a[0]); a[1] = fmaf(w3, f0.y, a[1]);
            a[2] = fmaf(w3, f1.x, a[2]); a[3] = fmaf(w3, f1.y, a[3]);
            a[4] = fmaf(w3, f2.x, a[4]); a[5] = fmaf(w3, f2.y, a[5]);
            a[6] = fmaf(w3, f3.x, a[6]); a[7] = fmaf(w3, f3.y, a[7]);
        }
    }
    *(float4*)&red[p * 128 + q * 8 + 0] = make_float4(a[0], a[1], a[2], a[3]);
    *(float4*)&red[p * 128 + q * 8 + 4] = make_float4(a[4], a[5], a[6], a[7]);
    __syncthreads();
    float sum = 0.f;
    #pragma unroll
    for (int pp = 0; pp < 8; ++pp) sum += red[pp * 128 + t];
    float v = sum + b1[t];
    h1s[t] = v > 0.f ? v : expm1f(v);   // ELU; h1 row lives only in LDS
    __syncthreads();
    // fused gemm2: xp2[d] = h1row @ W2 (128x32), K split across 4 thread-groups
    int c = t & 31, g = t >> 5;
    float part = 0.f;
    #pragma unroll 8
    for (int k = 0; k < 32; ++k)
        part = fmaf(h1s[g * 32 + k], W2[(size_t)(g * 32 + k) * 32 + c], part);
    red[t] = part;
    __syncthreads();
    if (t < 32) {
        float xv = red[t] + red[t + 32] + red[t + 64] + red[t + 96];
        xp2h[(size_t)d * 32 + t] = __float2half(xv);
        float ps = xv * a_s2[t], pd = xv * a_d2[t];
        #pragma unroll
        for (int m = 1; m < 32; m <<= 1) { ps += __shfl_xor(ps, m); pd += __shfl_xor(pd, m); }
        if (t == 0) { al_s2[d] = ps; al_d2[d] = pd; }
    }
    if (d == 0 && t < 32)                     // zero row N for edge2's padded gather
        xp2h[(size_t)N * 32 + t] = __float2half(0.f);
}

// ---------- edge2: softmax + branch-free padded 2-deep gather -> out [N,32] ----------
__global__ __launch_bounds__(128) void edge2_kernel(const int* __restrict__ cnt,
        const int* __restrict__ adj, const float* __restrict__ al_s,
        const float* __restrict__ al_d, const half_t* __restrict__ xp2h,
        const float* __restrict__ b2v, float* __restrict__ out, int N) {
    __shared__ int srcs[CAP];
    __shared__ float ew[CAP];
    __shared__ __align__(16) float red[32 * 32];
    __shared__ float red2[128];
    __shared__ float wden[2];
    int d = blockIdx.x, t = threadIdx.x;
    int deg = cnt[d]; if (deg > CAP) deg = CAP;
    float ex = 0.f;
    int s = N;
    if (t < deg) {
        s = adj[(size_t)d * CAP + t];
        ex = expf(lrelu(al_s[s] + al_d[d]));
    }
    srcs[t] = s;
    float r = ex;
    #pragma unroll
    for (int m = 1; m < 64; m <<= 1) r += __shfl_xor(r, m);
    if ((t & 63) == 0) wden[t >> 6] = r;
    __syncthreads();
    float den = wden[0] + wden[1];
    ew[t] = (t < deg) ? ex / (den + 1e-16f) : 0.f;
    __syncthreads();
    int q = t & 3, p = t >> 2;                // 4 lanes/edge, 32 edges per half-round
    float a[8] = {};
    const uint4* xr = (const uint4*)xp2h;     // row = 4 uint4
    int degp = (deg + 63) & ~63;
    for (int rr = 0; rr < degp; rr += 64) {
        int i0 = rr + p, i1 = i0 + 32;
        int s0 = srcs[i0], s1 = srcs[i1];
        uint4 v0 = xr[(size_t)s0 * 4 + q];
        uint4 v1 = xr[(size_t)s1 * 4 + q];
        float w0 = ew[i0], w1 = ew[i1];
        {
            float2 f0 = h2f2(v0.x), f1 = h2f2(v0.y), f2 = h2f2(v0.z), f3 = h2f2(v0.w);
            a[0] = fmaf(w0, f0.x, a[0]); a[1] = fmaf(w0, f0.y, a[1]);
            a[2] = fmaf(w0, f1.x, a[2]); a[3] = fmaf(w0, f1.y, a[3]);
            a[4] = fmaf(w0, f2.x, a[4]); a[5] = fmaf(w0, f2.y, a[5]);
            a[6] = fmaf(w0, f3.x, a[6]); a[7] = fmaf(w0, f3.y, a[7]);
        }
        {
            float2 f0 = h2f2(v1.x), f1 = h2f2(v1.y), f2 = h2f2(v1.z), f3 = h2f2(v1.w);
            a[0] = fmaf(w1, f0.x, a[0]); a[1] = fmaf(w1, f0.y, a[1]);
            a[2] = fmaf(w1, f1.x, a[2]); a[3] = fmaf(w1, f1.y, a[3]);
            a[4] = fmaf(w1, f2.x, a[4]); a[5] = fmaf(w1, f2.y, a[5]);
            a[6] = fmaf(w1, f3.x, a[6]); a[7] = fmaf(w1, f3.y, a[7]);
        }
    }
    *(float4*)&red[p * 32 + q * 8 + 0] = make_float4(a[0], a[1], a[2], a[3]);
    *(float4*)&red[p * 32 + q * 8 + 4] = make_float4(a[4], a[5], a[6], a[7]);
    __syncthreads();
    int c = t & 31, g = t >> 5;
    float part = 0.f;
    #pragma unroll
    for (int k = 0; k < 8; ++k) part += red[(g * 8 + k) * 32 + c];
    red2[t] = part;
    __syncthreads();
    if (t < 32) {
        float s2 = red2[t] + red2[t + 32] + red2[t + 64] + red2[t + 96];
        out[(size_t)d * 32 + t] = s2 + b2v[t];
    }
}

extern "C" void kernel_launch(void* const* d_in, const int* in_sizes, int n_in,
                              void* d_out, int out_size, void* d_ws, size_t ws_size,
                              hipStream_t stream) {
    const float* x    = (const float*)d_in[0];
    const int*   ei   = (const int*)d_in[1];
    const float* W1   = (const float*)d_in[2];
    const float* a_s1 = (const float*)d_in[3];
    const float* a_d1 = (const float*)d_in[4];
    const float* b1   = (const float*)d_in[5];
    const float* W2   = (const float*)d_in[6];
    const float* a_s2 = (const float*)d_in[7];
    const float* a_d2 = (const float*)d_in[8];
    const float* b2   = (const float*)d_in[9];
    int N = in_sizes[0] / 128;
    int E = in_sizes[1] / 2;
    float* out = (float*)d_out;

    int shift = 0;
    while (((N - 1) >> shift) >= NB) shift++;

    char* wsb = (char*)d_ws;
    size_t off = 0;
    auto alloc = [&](size_t bytes) -> void* {
        void* p = wsb + off;
        off = (off + bytes + 255) & ~(size_t)255;
        return p;
    };
    int*    cnt      = (int*)   alloc((size_t)N * 4);
    int*    adj      = (int*)   alloc((size_t)N * CAP * 4);
    int*    partials = (int*)   alloc((size_t)GAB * NB * 4);
    int*    bin_base = (int*)   alloc((size_t)(NB + 1) * 4);
    int2*   binned   = (int2*)  alloc((size_t)(E + N) * 8);
    half_t* xp1h     = (half_t*)alloc((size_t)(N + 1) * 128 * 2);   // +1 zero row
    float*  al_s1    = (float*) alloc((size_t)N * 4 * 4);
    float*  al_d1    = (float*) alloc((size_t)N * 4 * 4);
    half_t* xp2h     = (half_t*)alloc((size_t)(N + 1) * 32 * 2);    // +1 zero row
    float*  al_s2    = (float*) alloc((size_t)N * 4);
    float*  al_d2    = (float*) alloc((size_t)N * 4);

    k_count<<<GAB, 256, 0, stream>>>(ei, E, N, shift, partials, cnt);
    k_scan<<<1, 256, 0, stream>>>(partials, bin_base);
    k_bin<<<GAB, 256, 0, stream>>>(ei, E, N, shift, partials, binned);
    k_fill<<<NB * SUBS, 256, 0, stream>>>(binned, bin_base, cnt, adj);
    gemm1_kernel<<<(N + 31) / 32, 256, 0, stream>>>(x, W1, a_s1, a_d1, xp1h, al_s1, al_d1, N);
    edge1_kernel<<<N, 128, 0, stream>>>(cnt, adj, al_s1, al_d1, xp1h, b1,
                                        W2, a_s2, a_d2, xp2h, al_s2, al_d2, N);
    edge2_kernel<<<N, 128, 0, stream>>>(cnt, adj, al_s2, al_d2, xp2h, b2, out, N);
}

// Round 7
// 311.134 us; speedup vs baseline: 1.4686x; 1.0043x over previous
//
#include <hip/hip_runtime.h>
#include <hip/hip_fp16.h>

#define NEG_SLOPE 0.2f
#define CAP 128     // max in-degree slots; in-degree ~ Poisson(33), P(deg>96) ~ 1e-19
#define NB  64      // coarse dst bins
#define GAB 192     // blocks for count/bin passes
#define SUBS 32     // blocks per bin in fill phase

typedef __half half_t;

__device__ __forceinline__ float lrelu(float x) { return x >= 0.f ? x : NEG_SLOPE * x; }

__device__ __forceinline__ unsigned int f2h2(float a, float b) {
    union { unsigned int u; __half2 h; } v; v.h = __floats2half2_rn(a, b);
    return v.u;
}

// 8 half elements of v, scaled by w, accumulated into a[0..7].
// Element-wise __half2float + fmaf lets the compiler emit v_fma_mix_f32
// (fp16 source folded into the fp32 FMA) instead of separate v_cvt + v_fma.
__device__ __forceinline__ void fma8h(const uint4& v, float w, float* a) {
    const __half* hp = (const __half*)&v;
    #pragma unroll
    for (int j = 0; j < 8; ++j) a[j] = fmaf(w, __half2float(hp[j]), a[j]);
}

// int64 edge_index detection: odd int32 words of first 64 entries are all zero
__device__ __forceinline__ bool edge_is64(const int* __restrict__ ei, int E) {
    int t = threadIdx.x & 63;
    int idx = 2 * t + 1; if (idx >= 2 * E) idx = 2 * E - 1;
    unsigned long long b = __ballot(ei[idx] != 0);
    return b == 0ULL;
}

__device__ __forceinline__ void load_edge(const int* __restrict__ ei, int E, int i,
                                          bool is64, int& s, int& d) {
    if (i < E) {
        if (is64) { const long long* e = (const long long*)ei; s = (int)e[i]; d = (int)e[E + i]; }
        else      { s = ei[i]; d = ei[E + i]; }
    } else { s = d = i - E; }            // PyG add_self_loops
}

// ---------- phase 1: per-block per-bin counts (+ zero cnt for k_fill) ----------
__global__ __launch_bounds__(256) void k_count(const int* __restrict__ ei,
        int E, int N, int shift, int* __restrict__ partials, int* __restrict__ cnt) {
    __shared__ int cnts[NB];
    int t = threadIdx.x, b = blockIdx.x;
    if (t < NB) cnts[t] = 0;
    bool is64 = edge_is64(ei, E);
    for (int i = b * 256 + t; i < N; i += GAB * 256) cnt[i] = 0;
    __syncthreads();
    int tot = E + N;
    for (int i = b * 256 + t; i < tot; i += GAB * 256) {
        int s, d; load_edge(ei, E, i, is64, s, d);
        atomicAdd(&cnts[d >> shift], 1);
    }
    __syncthreads();
    if (t < NB) partials[b * NB + t] = cnts[t];
}

// ---------- phase 2: scan -> per-(block,bin) write offsets + bin bases ----------
__global__ __launch_bounds__(256) void k_scan(int* __restrict__ partials,
                                              int* __restrict__ bin_base) {
    __shared__ int lp[GAB * NB];    // 48KB
    __shared__ int tot[NB], base[NB];
    int t = threadIdx.x;
    for (int i = t; i < GAB * NB; i += 256) lp[i] = partials[i];
    __syncthreads();
    if (t < NB) {
        int run = 0;
        for (int b = 0; b < GAB; ++b) { int v = lp[b * NB + t]; lp[b * NB + t] = run; run += v; }
        tot[t] = run;
    }
    __syncthreads();
    if (t == 0) {
        int run = 0;
        for (int i = 0; i < NB; ++i) { base[i] = run; run += tot[i]; }
    }
    __syncthreads();
    if (t < NB) bin_base[t] = base[t];
    if (t == 0) bin_base[NB] = base[NB - 1] + tot[NB - 1];
    for (int i = t; i < GAB * NB; i += 256) partials[i] = lp[i] + base[i & (NB - 1)];
}

// ---------- phase 3: scatter edges into dst bins (LDS cursors) ----------
__global__ __launch_bounds__(256) void k_bin(const int* __restrict__ ei,
        int E, int N, int shift, const int* __restrict__ offsets, int2* __restrict__ binned) {
    __shared__ int cur[NB];
    int t = threadIdx.x, b = blockIdx.x;
    if (t < NB) cur[t] = offsets[b * NB + t];
    bool is64 = edge_is64(ei, E);
    __syncthreads();
    int tot = E + N;
    for (int i = b * 256 + t; i < tot; i += GAB * 256) {
        int s, d; load_edge(ei, E, i, is64, s, d);
        int pos = atomicAdd(&cur[d >> shift], 1);
        binned[pos] = make_int2(s, d);
    }
}

// ---------- phase 4: fill adj; bin -> fixed blockIdx%NB residue => XCD-local L2 ----------
__global__ __launch_bounds__(256) void k_fill(const int2* __restrict__ binned,
        const int* __restrict__ bin_base, int* __restrict__ cnt, int* __restrict__ adj) {
    int t = threadIdx.x;
    int bin = blockIdx.x & (NB - 1);
    int sub = blockIdx.x >> 6;
    int lo = bin_base[bin], hi = bin_base[bin + 1];
    for (int i = lo + sub * 256 + t; i < hi; i += SUBS * 256) {
        int2 e = binned[i];
        int pos = atomicAdd(&cnt[e.y], 1);
        if (pos < CAP) adj[(size_t)e.y * CAP + pos] = e.x;
    }
}

// ---------- GEMM1 + fused logits1, fp16 output (+ zero row N) ----------
__global__ __launch_bounds__(256) void gemm1_kernel(const float* __restrict__ x,
        const float* __restrict__ W1, const float* __restrict__ a_src,
        const float* __restrict__ a_dst, half_t* __restrict__ xp1h,
        float* __restrict__ al_s, float* __restrict__ al_d, int N) {
    __shared__ __align__(16) float ws[64 * 128];
    __shared__ __align__(16) float xst[128 * 36];
    int t = threadIdx.x;
    int row0 = blockIdx.x * 32;
    if (blockIdx.x == 0 && t < 16)     // zero row N for padded gathers
        ((uint4*)(xp1h + (size_t)N * 128))[t] = make_uint4(0, 0, 0, 0);
    #pragma unroll
    for (int ii = 0; ii < 4; ++ii) {
        int idx = t + 256 * ii;
        int r = idx >> 5, kq = idx & 31;
        int n = row0 + r;
        float4 v = make_float4(0.f, 0.f, 0.f, 0.f);
        if (n < N) v = *(const float4*)&x[(size_t)n * 128 + kq * 4];
        xst[(kq * 4 + 0) * 36 + r] = v.x;
        xst[(kq * 4 + 1) * 36 + r] = v.y;
        xst[(kq * 4 + 2) * 36 + r] = v.z;
        xst[(kq * 4 + 3) * 36 + r] = v.w;
    }
    int cg = t & 31, rg = t >> 5;
    float acc[4][4] = {};
    for (int half = 0; half < 2; ++half) {
        __syncthreads();
        const float4* wsrc = (const float4*)(W1 + half * 64 * 128);
        float4* wdst = (float4*)ws;
        #pragma unroll
        for (int ii = 0; ii < 8; ++ii) wdst[t + 256 * ii] = wsrc[t + 256 * ii];
        __syncthreads();
        #pragma unroll 4
        for (int k = 0; k < 64; ++k) {
            float4 wv = *(const float4*)&ws[k * 128 + cg * 4];
            float4 xv = *(const float4*)&xst[(half * 64 + k) * 36 + rg * 4];
            float xr[4] = {xv.x, xv.y, xv.z, xv.w};
            float wr[4] = {wv.x, wv.y, wv.z, wv.w};
            #pragma unroll
            for (int r = 0; r < 4; ++r)
                #pragma unroll
                for (int c = 0; c < 4; ++c)
                    acc[r][c] = fmaf(xr[r], wr[c], acc[r][c]);
        }
    }
    #pragma unroll
    for (int r = 0; r < 4; ++r) {
        int n = row0 + rg * 4 + r;
        if (n < N) {
            uint2 u = make_uint2(f2h2(acc[r][0], acc[r][1]), f2h2(acc[r][2], acc[r][3]));
            *(uint2*)&xp1h[(size_t)n * 128 + cg * 4] = u;
        }
    }
    float ps[4], pd[4];
    #pragma unroll
    for (int r = 0; r < 4; ++r) {
        float s = 0.f, dd = 0.f;
        #pragma unroll
        for (int c = 0; c < 4; ++c) {
            s  = fmaf(acc[r][c], a_src[cg * 4 + c], s);
            dd = fmaf(acc[r][c], a_dst[cg * 4 + c], dd);
        }
        ps[r] = s; pd[r] = dd;
    }
    #pragma unroll
    for (int m = 1; m < 8; m <<= 1) {
        #pragma unroll
        for (int r = 0; r < 4; ++r) { ps[r] += __shfl_xor(ps[r], m); pd[r] += __shfl_xor(pd[r], m); }
    }
    if ((cg & 7) == 0) {
        int head = cg >> 3;
        #pragma unroll
        for (int r = 0; r < 4; ++r) {
            int n = row0 + rg * 4 + r;
            if (n < N) { al_s[n * 4 + head] = ps[r]; al_d[n * 4 + head] = pd[r]; }
        }
    }
}

// ---------- edge1: softmax + gather (4-deep full rounds, 2-deep tail) + fused gemm2 ----------
__global__ __launch_bounds__(128) void edge1_kernel(const int* __restrict__ cnt,
        const int* __restrict__ adj, const float* __restrict__ al_s,
        const float* __restrict__ al_d, const half_t* __restrict__ xp1h,
        const float* __restrict__ b1, const float* __restrict__ W2,
        const float* __restrict__ a_s2, const float* __restrict__ a_d2,
        half_t* __restrict__ xp2h, float* __restrict__ al_s2, float* __restrict__ al_d2,
        int N) {
    __shared__ int srcs[CAP];
    __shared__ float ew[CAP * 4];
    __shared__ __align__(16) float red[8 * 128];
    __shared__ float h1s[128];
    __shared__ float4 wden[2];
    int d = blockIdx.x, t = threadIdx.x;
    int deg = cnt[d]; if (deg > CAP) deg = CAP;
    float4 ex = make_float4(0.f, 0.f, 0.f, 0.f);
    int s = N;                              // pad slots gather the zero row
    if (t < deg) {
        s = adj[(size_t)d * CAP + t];
        float4 as = *(const float4*)&al_s[s * 4];
        float4 ad = *(const float4*)&al_d[d * 4];
        ex.x = expf(lrelu(as.x + ad.x));
        ex.y = expf(lrelu(as.y + ad.y));
        ex.z = expf(lrelu(as.z + ad.z));
        ex.w = expf(lrelu(as.w + ad.w));
    }
    srcs[t] = s;
    float4 r = ex;
    #pragma unroll
    for (int m = 1; m < 64; m <<= 1) {
        r.x += __shfl_xor(r.x, m); r.y += __shfl_xor(r.y, m);
        r.z += __shfl_xor(r.z, m); r.w += __shfl_xor(r.w, m);
    }
    if ((t & 63) == 0) wden[t >> 6] = r;
    __syncthreads();
    float4 den = wden[0], dn1 = wden[1];
    den.x += dn1.x; den.y += dn1.y; den.z += dn1.z; den.w += dn1.w;
    float4 al = make_float4(0.f, 0.f, 0.f, 0.f);   // pad slots get weight 0
    if (t < deg) {
        al.x = ex.x / (den.x + 1e-16f); al.y = ex.y / (den.y + 1e-16f);
        al.z = ex.z / (den.z + 1e-16f); al.w = ex.w / (den.w + 1e-16f);
    }
    *(float4*)&ew[t * 4] = al;
    __syncthreads();
    // gather: 16 lanes/edge; main loop = 4-deep over FULL 32-edge rounds (no pad),
    // tail = 2-deep padded to 16 (pad slots hit the L1-resident zero row, weight 0)
    int q = t & 15, p = t >> 4, h = q >> 2;
    float a[8] = {};
    const uint4* xr = (const uint4*)xp1h;     // row = 16 uint4
    int rr = 0;
    for (; rr + 32 <= deg; rr += 32) {
        int i0 = rr + p, i1 = i0 + 8, i2 = i0 + 16, i3 = i0 + 24;
        uint4 v0 = xr[(size_t)srcs[i0] * 16 + q];
        uint4 v1 = xr[(size_t)srcs[i1] * 16 + q];
        uint4 v2 = xr[(size_t)srcs[i2] * 16 + q];
        uint4 v3 = xr[(size_t)srcs[i3] * 16 + q];
        float w0 = ew[i0 * 4 + h], w1 = ew[i1 * 4 + h];
        float w2 = ew[i2 * 4 + h], w3 = ew[i3 * 4 + h];
        fma8h(v0, w0, a); fma8h(v1, w1, a); fma8h(v2, w2, a); fma8h(v3, w3, a);
    }
    int degp = (deg + 15) & ~15;
    for (; rr < degp; rr += 16) {
        int i0 = rr + p, i1 = i0 + 8;
        uint4 v0 = xr[(size_t)srcs[i0] * 16 + q];
        uint4 v1 = xr[(size_t)srcs[i1] * 16 + q];
        float w0 = ew[i0 * 4 + h], w1 = ew[i1 * 4 + h];
        fma8h(v0, w0, a); fma8h(v1, w1, a);
    }
    *(float4*)&red[p * 128 + q * 8 + 0] = make_float4(a[0], a[1], a[2], a[3]);
    *(float4*)&red[p * 128 + q * 8 + 4] = make_float4(a[4], a[5], a[6], a[7]);
    __syncthreads();
    float sum = 0.f;
    #pragma unroll
    for (int pp = 0; pp < 8; ++pp) sum += red[pp * 128 + t];
    float v = sum + b1[t];
    h1s[t] = v > 0.f ? v : expm1f(v);   // ELU; h1 row lives only in LDS
    __syncthreads();
    // fused gemm2: xp2[d] = h1row @ W2 (128x32), K split across 4 thread-groups
    int c = t & 31, g = t >> 5;
    float part = 0.f;
    #pragma unroll 8
    for (int k = 0; k < 32; ++k)
        part = fmaf(h1s[g * 32 + k], W2[(size_t)(g * 32 + k) * 32 + c], part);
    red[t] = part;
    __syncthreads();
    if (t < 32) {
        float xv = red[t] + red[t + 32] + red[t + 64] + red[t + 96];
        xp2h[(size_t)d * 32 + t] = __float2half(xv);
        float ps = xv * a_s2[t], pd = xv * a_d2[t];
        #pragma unroll
        for (int m = 1; m < 32; m <<= 1) { ps += __shfl_xor(ps, m); pd += __shfl_xor(pd, m); }
        if (t == 0) { al_s2[d] = ps; al_d2[d] = pd; }
    }
    if (d == 0 && t < 32)                     // zero row N for edge2's padded gather
        xp2h[(size_t)N * 32 + t] = __float2half(0.f);
}

// ---------- edge2: softmax + gather (wave-uniform small/large path) -> out [N,32] ----------
__global__ __launch_bounds__(128) void edge2_kernel(const int* __restrict__ cnt,
        const int* __restrict__ adj, const float* __restrict__ al_s,
        const float* __restrict__ al_d, const half_t* __restrict__ xp2h,
        const float* __restrict__ b2v, float* __restrict__ out, int N) {
    __shared__ int srcs[CAP];
    __shared__ float ew[CAP];
    __shared__ __align__(16) float red[32 * 32];
    __shared__ float red2[128];
    __shared__ float wden[2];
    int d = blockIdx.x, t = threadIdx.x;
    int deg = cnt[d]; if (deg > CAP) deg = CAP;
    float ex = 0.f;
    int s = N;
    if (t < deg) {
        s = adj[(size_t)d * CAP + t];
        ex = expf(lrelu(al_s[s] + al_d[d]));
    }
    srcs[t] = s;
    float r = ex;
    #pragma unroll
    for (int m = 1; m < 64; m <<= 1) r += __shfl_xor(r, m);
    if ((t & 63) == 0) wden[t >> 6] = r;
    __syncthreads();
    float den = wden[0] + wden[1];
    ew[t] = (t < deg) ? ex / (den + 1e-16f) : 0.f;
    __syncthreads();
    int q = t & 3, p = t >> 2;                // 4 lanes/edge, 32 edge slots
    float a[8] = {};
    const uint4* xr = (const uint4*)xp2h;     // row = 4 uint4
    if (deg <= 32) {                           // wave-uniform: 47% of blocks
        uint4 v0 = xr[(size_t)srcs[p] * 4 + q];
        fma8h(v0, ew[p], a);
    } else {
        int degp = (deg + 63) & ~63;
        for (int rr = 0; rr < degp; rr += 64) {
            int i0 = rr + p, i1 = i0 + 32;
            uint4 v0 = xr[(size_t)srcs[i0] * 4 + q];
            uint4 v1 = xr[(size_t)srcs[i1] * 4 + q];
            float w0 = ew[i0], w1 = ew[i1];
            fma8h(v0, w0, a); fma8h(v1, w1, a);
        }
    }
    *(float4*)&red[p * 32 + q * 8 + 0] = make_float4(a[0], a[1], a[2], a[3]);
    *(float4*)&red[p * 32 + q * 8 + 4] = make_float4(a[4], a[5], a[6], a[7]);
    __syncthreads();
    int c = t & 31, g = t >> 5;
    float part = 0.f;
    #pragma unroll
    for (int k = 0; k < 8; ++k) part += red[(g * 8 + k) * 32 + c];
    red2[t] = part;
    __syncthreads();
    if (t < 32) {
        float s2 = red2[t] + red2[t + 32] + red2[t + 64] + red2[t + 96];
        out[(size_t)d * 32 + t] = s2 + b2v[t];
    }
}

extern "C" void kernel_launch(void* const* d_in, const int* in_sizes, int n_in,
                              void* d_out, int out_size, void* d_ws, size_t ws_size,
                              hipStream_t stream) {
    const float* x    = (const float*)d_in[0];
    const int*   ei   = (const int*)d_in[1];
    const float* W1   = (const float*)d_in[2];
    const float* a_s1 = (const float*)d_in[3];
    const float* a_d1 = (const float*)d_in[4];
    const float* b1   = (const float*)d_in[5];
    const float* W2   = (const float*)d_in[6];
    const float* a_s2 = (const float*)d_in[7];
    const float* a_d2 = (const float*)d_in[8];
    const float* b2   = (const float*)d_in[9];
    int N = in_sizes[0] / 128;
    int E = in_sizes[1] / 2;
    float* out = (float*)d_out;

    int shift = 0;
    while (((N - 1) >> shift) >= NB) shift++;

    char* wsb = (char*)d_ws;
    size_t off = 0;
    auto alloc = [&](size_t bytes) -> void* {
        void* p = wsb + off;
        off = (off + bytes + 255) & ~(size_t)255;
        return p;
    };
    int*    cnt      = (int*)   alloc((size_t)N * 4);
    int*    adj      = (int*)   alloc((size_t)N * CAP * 4);
    int*    partials = (int*)   alloc((size_t)GAB * NB * 4);
    int*    bin_base = (int*)   alloc((size_t)(NB + 1) * 4);
    int2*   binned   = (int2*)  alloc((size_t)(E + N) * 8);
    half_t* xp1h     = (half_t*)alloc((size_t)(N + 1) * 128 * 2);   // +1 zero row
    float*  al_s1    = (float*) alloc((size_t)N * 4 * 4);
    float*  al_d1    = (float*) alloc((size_t)N * 4 * 4);
    half_t* xp2h     = (half_t*)alloc((size_t)(N + 1) * 32 * 2);    // +1 zero row
    float*  al_s2    = (float*) alloc((size_t)N * 4);
    float*  al_d2    = (float*) alloc((size_t)N * 4);

    k_count<<<GAB, 256, 0, stream>>>(ei, E, N, shift, partials, cnt);
    k_scan<<<1, 256, 0, stream>>>(partials, bin_base);
    k_bin<<<GAB, 256, 0, stream>>>(ei, E, N, shift, partials, binned);
    k_fill<<<NB * SUBS, 256, 0, stream>>>(binned, bin_base, cnt, adj);
    gemm1_kernel<<<(N + 31) / 32, 256, 0, stream>>>(x, W1, a_s1, a_d1, xp1h, al_s1, al_d1, N);
    edge1_kernel<<<N, 128, 0, stream>>>(cnt, adj, al_s1, al_d1, xp1h, b1,
                                        W2, a_s2, a_d2, xp2h, al_s2, al_d2, N);
    edge2_kernel<<<N, 128, 0, stream>>>(cnt, adj, al_s2, al_d2, xp2h, b2, out, N);
}